// Round 5
// baseline (3106.737 us; speedup 1.0000x reference)
//
#include <hip/hip_runtime.h>
#include <math.h>

#define NN 50000
#define EE 800000
#define NPAIR 200000

__device__ __forceinline__ float leaky(float x){ return x >= 0.f ? x : 0.2f*x; }

// ---------------- degree / norms / CSR build ----------------

__global__ void degree_kernel(const int* __restrict__ src, const int* __restrict__ dst,
                              int* cnt_out, int* cnt_in){
  int i = blockIdx.x*blockDim.x + threadIdx.x;
  if(i < EE){
    atomicAdd(&cnt_out[src[i]], 1);
    atomicAdd(&cnt_in[dst[i]], 1);
  }
}

__global__ void norm_kernel(const int* __restrict__ cnt_out, const int* __restrict__ cnt_in,
                            float* __restrict__ out_norm, float* __restrict__ in_norm){
  int i = blockIdx.x*blockDim.x + threadIdx.x;
  if(i < NN){
    int o = cnt_out[i]; if(o < 1) o = 1;
    int d = cnt_in[i];  if(d < 1) d = 1;
    out_norm[i] = 1.f/sqrtf((float)o);
    in_norm[i]  = 1.f/sqrtf((float)d);
  }
}

// single-block exclusive scan of cnt_in[NN] -> row_off[NN+1]
__global__ void scan_kernel(const int* __restrict__ cnt, int* __restrict__ row_off){
  const int T = 512;
  __shared__ int sums[T];
  int t = threadIdx.x;
  int chunk = (NN + T - 1)/T;
  int base = t*chunk;
  int hi = base + chunk; if(hi > NN) hi = NN;
  int s = 0;
  for(int i = base; i < hi; i++) s += cnt[i];
  sums[t] = s;
  __syncthreads();
  for(int off = 1; off < T; off <<= 1){
    int add = (t >= off) ? sums[t-off] : 0;
    __syncthreads();
    sums[t] += add;
    __syncthreads();
  }
  int run = sums[t] - s;   // exclusive prefix of this thread's chunk
  for(int i = base; i < hi; i++){ row_off[i] = run; run += cnt[i]; }
  if(t == T-1) row_off[NN] = EE;
}

// ew2 = w * out_norm[src]: out_norm commutes with @W, so fold it into the
// edge weight once — removes the scale_rows pass and all GEMM prescales.
__global__ void bucket_kernel(const int* __restrict__ src, const int* __restrict__ dst,
                              const float* __restrict__ w, const float* __restrict__ out_norm,
                              const int* __restrict__ row_off,
                              int* fill, int* __restrict__ es, float* __restrict__ ew){
  int i = blockIdx.x*blockDim.x + threadIdx.x;
  if(i < EE){
    int d = dst[i];
    int s = src[i];
    int p = row_off[d] + atomicAdd(&fill[d], 1);
    es[p] = s;
    ew[p] = w[i] * out_norm[s];
  }
}

// P1 (160x80) -> P1t (80x160), P2 (80x40) -> P2t (40x80): makes each output
// column's weights contiguous so the predictor's uniform loads merge into
// wide s_load_dwordxN.
__global__ void transposeP_kernel(const float* __restrict__ P1, const float* __restrict__ P2,
                                  float* __restrict__ P1t, float* __restrict__ P2t){
  int i = blockIdx.x*256 + threadIdx.x;
  if(i < 160*80){ int k = i/80, c = i - k*80; P1t[c*160 + k] = P1[i]; }
  if(i < 80*40){ int k = i/40, c = i - k*40; P2t[c*80 + k] = P2[i]; }
}

// ---------------- aggregation v2 (dst-CSR, float4, 4 edges in flight) ----------
// MODE 0: plain sum; MODE 1: relu(sum*in_norm[v] + bias); MODE 2: sum*in_norm[v]+bias
template<int F, int MODE>
__global__ __launch_bounds__(256) void agg_kernel(
    const float* __restrict__ feat, const int* __restrict__ es,
    const float* __restrict__ ew, const int* __restrict__ row_off,
    const float* __restrict__ innorm, const float* __restrict__ bias,
    float* __restrict__ out){
  constexpr int F4 = F/4;                 // 64 (F=256) or 40 (F=160)
  __shared__ float4 red[4*F4];
  int tid = threadIdx.x;
  int w = tid >> 6, lane = tid & 63;
  int v = blockIdx.x;
  int s = row_off[v], e = row_off[v+1];
  if(lane < F4){
    const float4* f4 = (const float4*)feat;
    float4 acc0 = {0,0,0,0}, acc1 = {0,0,0,0};
    int j = s + w;
    for(; j + 4 < e; j += 8){
      int u0 = es[j];   float w0 = ew[j];
      int u1 = es[j+4]; float w1 = ew[j+4];
      float4 a = f4[(size_t)u0*F4 + lane];
      float4 b = f4[(size_t)u1*F4 + lane];
      acc0.x += a.x*w0; acc0.y += a.y*w0; acc0.z += a.z*w0; acc0.w += a.w*w0;
      acc1.x += b.x*w1; acc1.y += b.y*w1; acc1.z += b.z*w1; acc1.w += b.w*w1;
    }
    if(j < e){
      int u = es[j]; float wt = ew[j];
      float4 a = f4[(size_t)u*F4 + lane];
      acc0.x += a.x*wt; acc0.y += a.y*wt; acc0.z += a.z*wt; acc0.w += a.w*wt;
    }
    acc0.x += acc1.x; acc0.y += acc1.y; acc0.z += acc1.z; acc0.w += acc1.w;
    red[w*F4 + lane] = acc0;
  }
  __syncthreads();
  if(tid < F4){
    float4 r0 = red[tid], r1 = red[F4+tid], r2 = red[2*F4+tid], r3 = red[3*F4+tid];
    float4 r;
    r.x = r0.x+r1.x+r2.x+r3.x;
    r.y = r0.y+r1.y+r2.y+r3.y;
    r.z = r0.z+r1.z+r2.z+r3.z;
    r.w = r0.w+r1.w+r2.w+r3.w;
    if(MODE >= 1){
      float inm = innorm[v];
      float4 bb = *(const float4*)&bias[tid*4];
      r.x = r.x*inm + bb.x; r.y = r.y*inm + bb.y;
      r.z = r.z*inm + bb.z; r.w = r.w*inm + bb.w;
      if(MODE == 1){
        r.x = fmaxf(r.x, 0.f); r.y = fmaxf(r.y, 0.f);
        r.z = fmaxf(r.z, 0.f); r.w = fmaxf(r.w, 0.f);
      }
    }
    ((float4*)(out + (size_t)v*F))[tid] = r;
  }
}

// ---------------- fp32 tiled GEMM v2: 128x128 tile, 8x8 microtile -------------
// C[N x M] = A @ B ; EPI: C = relu(C*in_norm[row] + bias[col])
// NOTE: no min-waves clamp — (256,4) forced a 64-VGPR cap and spilled the
// 8x8 accumulator to scratch (R3: 3.7 GB HBM traffic/dispatch, 950 us).
template<bool EPI>
__global__ __launch_bounds__(256) void gemm_kernel(
    const float* __restrict__ A, const float* __restrict__ B, float* __restrict__ C,
    int K, int M, const float* __restrict__ innorm, const float* __restrict__ bias){
  __shared__ float As[16][132];   // [k][row], +4 pad
  __shared__ float Bs[16][128];   // [k][col]
  int tid = threadIdx.x;
  int row0 = blockIdx.x*128, col0 = blockIdx.y*128;
  int arow = tid >> 1, ak = (tid & 1)*8;
  int grow = row0 + arow;
  int bcol = (tid & 31)*4, brow = tid >> 5;
  int tr = tid >> 4, tc = tid & 15;
  float acc[8][8] = {};
  const float* Arow = A + (size_t)grow*K;
  bool bvalid = (col0 + bcol + 3 < M);

  for(int k0 = 0; k0 < K; k0 += 16){
    float4 av0 = {0,0,0,0}, av1 = {0,0,0,0};
    if(grow < NN){
      av0 = *(const float4*)&Arow[k0 + ak];
      av1 = *(const float4*)&Arow[k0 + ak + 4];
    }
    float4 bv0 = {0,0,0,0}, bv1 = {0,0,0,0};
    if(bvalid){
      bv0 = *(const float4*)&B[(size_t)(k0+brow)*M + col0 + bcol];
      bv1 = *(const float4*)&B[(size_t)(k0+brow+8)*M + col0 + bcol];
    }
    __syncthreads();   // previous iter's reads done before overwrite
    As[ak+0][arow] = av0.x; As[ak+1][arow] = av0.y;
    As[ak+2][arow] = av0.z; As[ak+3][arow] = av0.w;
    As[ak+4][arow] = av1.x; As[ak+5][arow] = av1.y;
    As[ak+6][arow] = av1.z; As[ak+7][arow] = av1.w;
    *(float4*)&Bs[brow][bcol]   = bv0;
    *(float4*)&Bs[brow+8][bcol] = bv1;
    __syncthreads();
    #pragma unroll
    for(int k = 0; k < 16; k++){
      float4 a0 = *(const float4*)&As[k][tr*8];
      float4 a1 = *(const float4*)&As[k][tr*8 + 4];
      float4 b0 = *(const float4*)&Bs[k][tc*8];
      float4 b1 = *(const float4*)&Bs[k][tc*8 + 4];
      float a[8] = {a0.x,a0.y,a0.z,a0.w,a1.x,a1.y,a1.z,a1.w};
      float b[8] = {b0.x,b0.y,b0.z,b0.w,b1.x,b1.y,b1.z,b1.w};
      #pragma unroll
      for(int i = 0; i < 8; i++)
        #pragma unroll
        for(int j = 0; j < 8; j++)
          acc[i][j] += a[i]*b[j];
    }
  }

  bool fullc = (col0 + 128 <= M);
  #pragma unroll
  for(int i = 0; i < 8; i++){
    int r = row0 + tr*8 + i;
    if(r >= NN) continue;
    float inm = EPI ? innorm[r] : 1.f;
    int c0 = col0 + tc*8;
    float vals[8];
    #pragma unroll
    for(int j = 0; j < 8; j++){
      float vv = acc[i][j];
      if(EPI){ vv = fmaxf(vv*inm + bias[c0 + j], 0.f); }
      vals[j] = vv;
    }
    if(fullc){
      *(float4*)&C[(size_t)r*M + c0]     = make_float4(vals[0],vals[1],vals[2],vals[3]);
      *(float4*)&C[(size_t)r*M + c0 + 4] = make_float4(vals[4],vals[5],vals[6],vals[7]);
    }else{
      #pragma unroll
      for(int j = 0; j < 8; j++){
        int c = c0 + j;
        if(c < M) C[(size_t)r*M + c] = vals[j];
      }
    }
  }
}

// ---------------- predictor v3: one pair per lane, z in VGPRs ----------------
// Stage-1 was LDS-throughput-bound (R4: 26240 LDS-cyc/block == 257 us measured).
// Now: z[160] lives in registers, P1t/P2t columns are contiguous and read via
// wave-uniform scalar loads (s_load, one SGPR operand per v_fma) -> the only
// LDS use is the y1 dynamic-index round-trip (per-lane row, no barrier).
// Grid: 400000/128 = 3125 blocks exactly, no tail.
__global__ __launch_bounds__(128) void predictor_kernel(
    const float* __restrict__ h3,
    const int* __restrict__ ps, const int* __restrict__ pd,
    const int* __restrict__ ns, const int* __restrict__ nd,
    const float* __restrict__ P1t, const float* __restrict__ pb1,
    const float* __restrict__ P2t, const float* __restrict__ pb2,
    const float* __restrict__ P3, const float* __restrict__ pb3,
    float* __restrict__ out){
  __shared__ float y1L[128*80];    // 40960 B -> 4 blocks/CU
  int tid = threadIdx.x;
  int q = blockIdx.x*128 + tid;
  int a, b;
  if(q < NPAIR){ a = ps[q]; b = pd[q]; }
  else         { a = ns[q-NPAIR]; b = nd[q-NPAIR]; }
  const float4* ra = (const float4*)(h3 + (size_t)a*160);
  const float4* rb = (const float4*)(h3 + (size_t)b*160);
  float4 z[40];                    // 160 VGPRs, constant-indexed only
  #pragma unroll
  for(int i = 0; i < 40; i++){
    float4 va = ra[i], vb = rb[i];
    z[i] = make_float4(va.x*vb.x, va.y*vb.y, va.z*vb.z, va.w*vb.w);
  }
  float* myY = &y1L[tid*80];       // stride 80: (16*tid+c)%32 -> 2-way max (free)

  // stage 1: 2 cols/iter, 4 indep FMA chains per col (hide 4-cy dep latency)
  for(int c = 0; c < 80; c += 2){
    const float4* pc0 = (const float4*)(P1t + (c+0)*160);  // uniform -> s_load
    const float4* pc1 = (const float4*)(P1t + (c+1)*160);
    float a00=0,a01=0,a02=0,a03=0, a10=0,a11=0,a12=0,a13=0;
    #pragma unroll
    for(int i = 0; i < 40; i++){
      float4 p0 = pc0[i], p1 = pc1[i];
      a00 += z[i].x*p0.x; a01 += z[i].y*p0.y; a02 += z[i].z*p0.z; a03 += z[i].w*p0.w;
      a10 += z[i].x*p1.x; a11 += z[i].y*p1.y; a12 += z[i].z*p1.z; a13 += z[i].w*p1.w;
    }
    myY[c]   = leaky((a00+a01)+(a02+a03) + pb1[c]);
    myY[c+1] = leaky((a10+a11)+(a12+a13) + pb1[c+1]);
  }

  // reload y1 into constant-indexed regs (same lane wrote it; no barrier needed)
  float4 y1r[20];
  #pragma unroll
  for(int i = 0; i < 20; i++) y1r[i] = ((const float4*)myY)[i];

  // stage 2 + fused stage 3
  float res = pb3[0];
  for(int c = 0; c < 40; c += 2){
    const float4* pc0 = (const float4*)(P2t + (c+0)*80);
    const float4* pc1 = (const float4*)(P2t + (c+1)*80);
    float a00=0,a01=0,a02=0,a03=0, a10=0,a11=0,a12=0,a13=0;
    #pragma unroll
    for(int i = 0; i < 20; i++){
      float4 p0 = pc0[i], p1 = pc1[i];
      a00 += y1r[i].x*p0.x; a01 += y1r[i].y*p0.y; a02 += y1r[i].z*p0.z; a03 += y1r[i].w*p0.w;
      a10 += y1r[i].x*p1.x; a11 += y1r[i].y*p1.y; a12 += y1r[i].z*p1.z; a13 += y1r[i].w*p1.w;
    }
    float v0 = leaky((a00+a01)+(a02+a03) + pb2[c]);
    float v1 = leaky((a10+a11)+(a12+a13) + pb2[c+1]);
    res += v0*P3[c] + v1*P3[c+1];
  }
  out[q] = res;
}

// ---------------- launch ----------------

extern "C" void kernel_launch(void* const* d_in, const int* in_sizes, int n_in,
                              void* d_out, int out_size, void* d_ws, size_t ws_size,
                              hipStream_t stream) {
  const float* x  = (const float*)d_in[0];
  const float* w  = (const float*)d_in[1];
  const int* src  = (const int*)d_in[2];
  const int* dst  = (const int*)d_in[3];
  const int* ps   = (const int*)d_in[4];
  const int* pd   = (const int*)d_in[5];
  const int* ns   = (const int*)d_in[6];
  const int* nd   = (const int*)d_in[7];
  const float* W1 = (const float*)d_in[8];  const float* b1  = (const float*)d_in[9];
  const float* W2 = (const float*)d_in[10]; const float* b2  = (const float*)d_in[11];
  const float* W3 = (const float*)d_in[12]; const float* b3  = (const float*)d_in[13];
  const float* P1 = (const float*)d_in[14]; const float* pb1 = (const float*)d_in[15];
  const float* P2 = (const float*)d_in[16]; const float* pb2 = (const float*)d_in[17];
  const float* P3 = (const float*)d_in[18]; const float* pb3 = (const float*)d_in[19];
  float* out = (float*)d_out;

  char* p = (char*)d_ws;
  auto alloc = [&](size_t bytes)->char*{
    char* r = p; p += (bytes + 255) & ~(size_t)255; return r;
  };
  int*   cnt_out = (int*)  alloc(NN*4);          // these three must stay contiguous
  int*   cnt_in  = (int*)  alloc(NN*4);          // (zeroed with one memset)
  int*   fill    = (int*)  alloc(NN*4);
  int*   row_off = (int*)  alloc((NN+1)*4);
  float* out_nrm = (float*)alloc(NN*4);
  float* in_nrm  = (float*)alloc(NN*4);
  int*   es      = (int*)  alloc((size_t)EE*4);
  float* ew      = (float*)alloc((size_t)EE*4);
  float* P1t     = (float*)alloc(160*80*4);
  float* P2t     = (float*)alloc(80*40*4);
  float* bufA    = (float*)alloc((size_t)NN*512*4);  // h1 (N x 512)
  float* bufB    = (float*)alloc((size_t)NN*256*4);  // proj2 / proj3
  float* bufC    = (float*)alloc((size_t)NN*256*4);  // agg1 / h2

  size_t cntPad = (NN*4 + 255) & ~(size_t)255;
  hipMemsetAsync(cnt_out, 0, 3*cntPad, stream);

  degree_kernel<<<(EE+255)/256, 256, 0, stream>>>(src, dst, cnt_out, cnt_in);
  norm_kernel<<<(NN+255)/256, 256, 0, stream>>>(cnt_out, cnt_in, out_nrm, in_nrm);
  scan_kernel<<<1, 512, 0, stream>>>(cnt_in, row_off);
  bucket_kernel<<<(EE+255)/256, 256, 0, stream>>>(src, dst, w, out_nrm, row_off, fill, es, ew);
  transposeP_kernel<<<50, 256, 0, stream>>>(P1, P2, P1t, P2t);

  dim3 gA(391, 4), gB(391, 2);

  // layer 1: agg(x, ew2) @ W1, epilogue relu(*in_norm + b1)
  agg_kernel<256,0><<<NN, 256, 0, stream>>>(x, es, ew, row_off, nullptr, nullptr, bufC);
  gemm_kernel<true><<<gA, 256, 0, stream>>>(bufC, W1, bufA, 256, 512, in_nrm, b1);

  // layer 2: agg(h1 @ W2, ew2), fused epilogue relu(*in_norm + b2)
  gemm_kernel<false><<<gB, 256, 0, stream>>>(bufA, W2, bufB, 512, 256, nullptr, nullptr);
  agg_kernel<256,1><<<NN, 256, 0, stream>>>(bufB, es, ew, row_off, in_nrm, b2, bufC);

  // layer 3: agg(h2 @ W3, ew2), fused epilogue *in_norm + b3 -> d_out h region
  gemm_kernel<false><<<gB, 256, 0, stream>>>(bufC, W3, bufB, 256, 160, nullptr, nullptr);
  agg_kernel<160,2><<<NN, 256, 0, stream>>>(bufB, es, ew, row_off, in_nrm, b3, out + 2*NPAIR);

  // predictor on pos+neg pairs: one pair per lane
  predictor_kernel<<<(2*NPAIR)/128, 128, 0, stream>>>(out + 2*NPAIR, ps, pd, ns, nd,
                                                      P1t, pb1, P2t, pb2, P3, pb3, out);
}

// Round 6
// 1873.833 us; speedup vs baseline: 1.6580x; 1.6580x over previous
//
#include <hip/hip_runtime.h>
#include <math.h>

#define NN 50000
#define EE 800000
#define NPAIR 200000

__device__ __forceinline__ float leaky(float x){ return x >= 0.f ? x : 0.2f*x; }

// ---------------- degree / norms / CSR build ----------------

__global__ void degree_kernel(const int* __restrict__ src, const int* __restrict__ dst,
                              int* cnt_out, int* cnt_in){
  int i = blockIdx.x*blockDim.x + threadIdx.x;
  if(i < EE){
    atomicAdd(&cnt_out[src[i]], 1);
    atomicAdd(&cnt_in[dst[i]], 1);
  }
}

__global__ void norm_kernel(const int* __restrict__ cnt_out, const int* __restrict__ cnt_in,
                            float* __restrict__ out_norm, float* __restrict__ in_norm){
  int i = blockIdx.x*blockDim.x + threadIdx.x;
  if(i < NN){
    int o = cnt_out[i]; if(o < 1) o = 1;
    int d = cnt_in[i];  if(d < 1) d = 1;
    out_norm[i] = 1.f/sqrtf((float)o);
    in_norm[i]  = 1.f/sqrtf((float)d);
  }
}

// single-block exclusive scan of cnt_in[NN] -> row_off[NN+1]
__global__ void scan_kernel(const int* __restrict__ cnt, int* __restrict__ row_off){
  const int T = 512;
  __shared__ int sums[T];
  int t = threadIdx.x;
  int chunk = (NN + T - 1)/T;
  int base = t*chunk;
  int hi = base + chunk; if(hi > NN) hi = NN;
  int s = 0;
  for(int i = base; i < hi; i++) s += cnt[i];
  sums[t] = s;
  __syncthreads();
  for(int off = 1; off < T; off <<= 1){
    int add = (t >= off) ? sums[t-off] : 0;
    __syncthreads();
    sums[t] += add;
    __syncthreads();
  }
  int run = sums[t] - s;   // exclusive prefix of this thread's chunk
  for(int i = base; i < hi; i++){ row_off[i] = run; run += cnt[i]; }
  if(t == T-1) row_off[NN] = EE;
}

// ew2 = w * out_norm[src]: out_norm commutes with @W, folded into edge weight.
__global__ void bucket_kernel(const int* __restrict__ src, const int* __restrict__ dst,
                              const float* __restrict__ w, const float* __restrict__ out_norm,
                              const int* __restrict__ row_off,
                              int* fill, int* __restrict__ es, float* __restrict__ ew){
  int i = blockIdx.x*blockDim.x + threadIdx.x;
  if(i < EE){
    int d = dst[i];
    int s = src[i];
    int p = row_off[d] + atomicAdd(&fill[d], 1);
    es[p] = s;
    ew[p] = w[i] * out_norm[s];
  }
}

// ---------------- aggregation v2 (dst-CSR, float4, 4 edges in flight) ----------
// MODE 0: plain sum; MODE 1: relu(sum*in_norm[v] + bias); MODE 2: sum*in_norm[v]+bias
template<int F, int MODE>
__global__ __launch_bounds__(256) void agg_kernel(
    const float* __restrict__ feat, const int* __restrict__ es,
    const float* __restrict__ ew, const int* __restrict__ row_off,
    const float* __restrict__ innorm, const float* __restrict__ bias,
    float* __restrict__ out){
  constexpr int F4 = F/4;                 // 64 (F=256) or 40 (F=160)
  __shared__ float4 red[4*F4];
  int tid = threadIdx.x;
  int w = tid >> 6, lane = tid & 63;
  int v = blockIdx.x;
  int s = row_off[v], e = row_off[v+1];
  if(lane < F4){
    const float4* f4 = (const float4*)feat;
    float4 acc0 = {0,0,0,0}, acc1 = {0,0,0,0};
    int j = s + w;
    for(; j + 4 < e; j += 8){
      int u0 = es[j];   float w0 = ew[j];
      int u1 = es[j+4]; float w1 = ew[j+4];
      float4 a = f4[(size_t)u0*F4 + lane];
      float4 b = f4[(size_t)u1*F4 + lane];
      acc0.x += a.x*w0; acc0.y += a.y*w0; acc0.z += a.z*w0; acc0.w += a.w*w0;
      acc1.x += b.x*w1; acc1.y += b.y*w1; acc1.z += b.z*w1; acc1.w += b.w*w1;
    }
    if(j < e){
      int u = es[j]; float wt = ew[j];
      float4 a = f4[(size_t)u*F4 + lane];
      acc0.x += a.x*wt; acc0.y += a.y*wt; acc0.z += a.z*wt; acc0.w += a.w*wt;
    }
    acc0.x += acc1.x; acc0.y += acc1.y; acc0.z += acc1.z; acc0.w += acc1.w;
    red[w*F4 + lane] = acc0;
  }
  __syncthreads();
  if(tid < F4){
    float4 r0 = red[tid], r1 = red[F4+tid], r2 = red[2*F4+tid], r3 = red[3*F4+tid];
    float4 r;
    r.x = r0.x+r1.x+r2.x+r3.x;
    r.y = r0.y+r1.y+r2.y+r3.y;
    r.z = r0.z+r1.z+r2.z+r3.z;
    r.w = r0.w+r1.w+r2.w+r3.w;
    if(MODE >= 1){
      float inm = innorm[v];
      float4 bb = *(const float4*)&bias[tid*4];
      r.x = r.x*inm + bb.x; r.y = r.y*inm + bb.y;
      r.z = r.z*inm + bb.z; r.w = r.w*inm + bb.w;
      if(MODE == 1){
        r.x = fmaxf(r.x, 0.f); r.y = fmaxf(r.y, 0.f);
        r.z = fmaxf(r.z, 0.f); r.w = fmaxf(r.w, 0.f);
      }
    }
    ((float4*)(out + (size_t)v*F))[tid] = r;
  }
}

// ---------------- fp32 tiled GEMM v3: 128x128 tile, 8x16 microtile ------------
// 128 threads (2 waves). Per wave-k: 6 b128 LDS reads (72 cy) per 128 lane-FMA
// (256 VALU cy) -> ~89% VALU ceiling vs 66% for 8x8. B cols split 8+8
// (tc*8 and 64+tc*8) so Bs-read start banks are 2-way (free), not 4-way.
// ~200 VGPR expected (no launch_bounds min-waves clamp: R3 spill lesson).
template<bool EPI>
__global__ __launch_bounds__(128) void gemm_kernel(
    const float* __restrict__ A, const float* __restrict__ B, float* __restrict__ C,
    int K, int M, const float* __restrict__ innorm, const float* __restrict__ bias){
  __shared__ float As[16][132];   // [k][row], +4 pad
  __shared__ float Bs[16][132];   // [k][col], +4 pad
  int tid = threadIdx.x;
  int row0 = blockIdx.x*128, col0 = blockIdx.y*128;
  int grow = row0 + tid;                 // A staging: 1 row, 16 k per thread
  int bcol = (tid & 31)*4, brow = tid >> 5;   // B staging: 4 rows x float4
  int tr = tid >> 3, tc = tid & 7;       // microtile: rows tr*8..+7
  float acc[8][16] = {};
  const float* Arow = A + (size_t)grow*K;
  bool avalid = (grow < NN);
  bool bvalid = (col0 + bcol + 3 < M);

  for(int k0 = 0; k0 < K; k0 += 16){
    float4 a[4], b[4];
    #pragma unroll
    for(int r = 0; r < 4; r++){
      a[r] = avalid ? *(const float4*)&Arow[k0 + 4*r] : make_float4(0,0,0,0);
      b[r] = bvalid ? *(const float4*)&B[(size_t)(k0+brow+4*r)*M + col0 + bcol]
                    : make_float4(0,0,0,0);
    }
    __syncthreads();   // previous iter's reads done before overwrite
    #pragma unroll
    for(int r = 0; r < 4; r++){
      As[4*r+0][tid] = a[r].x; As[4*r+1][tid] = a[r].y;
      As[4*r+2][tid] = a[r].z; As[4*r+3][tid] = a[r].w;
      *(float4*)&Bs[brow+4*r][bcol] = b[r];
    }
    __syncthreads();
    #pragma unroll
    for(int k = 0; k < 16; k++){
      float4 a0 = *(const float4*)&As[k][tr*8];
      float4 a1 = *(const float4*)&As[k][tr*8 + 4];
      float4 b0 = *(const float4*)&Bs[k][tc*8];
      float4 b1 = *(const float4*)&Bs[k][tc*8 + 4];
      float4 b2 = *(const float4*)&Bs[k][64 + tc*8];
      float4 b3 = *(const float4*)&Bs[k][64 + tc*8 + 4];
      float av[8] = {a0.x,a0.y,a0.z,a0.w,a1.x,a1.y,a1.z,a1.w};
      float bv[16] = {b0.x,b0.y,b0.z,b0.w,b1.x,b1.y,b1.z,b1.w,
                      b2.x,b2.y,b2.z,b2.w,b3.x,b3.y,b3.z,b3.w};
      #pragma unroll
      for(int i = 0; i < 8; i++)
        #pragma unroll
        for(int j = 0; j < 16; j++)
          acc[i][j] += av[i]*bv[j];
    }
  }

  int c0a = col0 + tc*8;        // cols for j=0..7
  int c0b = col0 + 64 + tc*8;   // cols for j=8..15
  #pragma unroll
  for(int i = 0; i < 8; i++){
    int r = row0 + tr*8 + i;
    if(r >= NN) continue;
    float inm = EPI ? innorm[r] : 1.f;
    float vals[16];
    #pragma unroll
    for(int j = 0; j < 16; j++){
      float vv = acc[i][j];
      if(EPI){
        int c = (j < 8) ? c0a + j : c0b + (j-8);
        vv = fmaxf(vv*inm + bias[c], 0.f);
      }
      vals[j] = vv;
    }
    float* Cr = &C[(size_t)r*M];
    if(c0a + 7 < M){
      *(float4*)&Cr[c0a]   = make_float4(vals[0],vals[1],vals[2],vals[3]);
      *(float4*)&Cr[c0a+4] = make_float4(vals[4],vals[5],vals[6],vals[7]);
    }else{
      #pragma unroll
      for(int j = 0; j < 8; j++) if(c0a+j < M) Cr[c0a+j] = vals[j];
    }
    if(c0b + 7 < M){
      *(float4*)&Cr[c0b]   = make_float4(vals[8],vals[9],vals[10],vals[11]);
      *(float4*)&Cr[c0b+4] = make_float4(vals[12],vals[13],vals[14],vals[15]);
    }else{
      #pragma unroll
      for(int j = 0; j < 8; j++) if(c0b+j < M) Cr[c0b+j] = vals[8+j];
    }
  }
}

// ---------------- predictor v4: R4 structure, 4p x 10c microtile -------------
// 128 threads, 64 pairs/block. LDS 53760 B -> 3 blocks/CU (6 waves).
// Stage-1 per wave-k: z b128 (12cy) + P b128+b128+b64 (32cy) for 40 lane-FMA;
// 2 waves/block -> ~20.2 kcyc/block LDS model (R4 model verified within 4%).
// All strides 68 (mod 32 = 4 -> <=2-way bank aliasing, free per m136).
#define ZS 68
__global__ __launch_bounds__(128) void predictor_kernel(
    const float* __restrict__ h3,
    const int* __restrict__ ps, const int* __restrict__ pd,
    const int* __restrict__ ns, const int* __restrict__ nd,
    const float* __restrict__ P1, const float* __restrict__ pb1,
    const float* __restrict__ P2, const float* __restrict__ pb2,
    const float* __restrict__ P3, const float* __restrict__ pb3,
    float* __restrict__ out){
  __shared__ float smem[13440];      // 53760 B
  float* z   = smem;                 // [160][ZS]
  float* p1p = smem + 160*ZS;        // [32][80] k-panel @10880
  float* y1  = smem;                 // phase B: [80][ZS] cols-major (col=row idx)
  float* p2L = smem + 80*ZS;         // [80][40] @5440
  int tid = threadIdx.x;
  int pair0 = blockIdx.x*64;         // grid = 2*NPAIR/64 = 6250 exactly

  // --- gather h3 rows, z[k][p] = ha[k]*hb[k] (transposed, 2-way max) ---
  {
    int p = tid >> 1, sub = tid & 1;
    int q = pair0 + p;
    int a, b;
    if(q < NPAIR){ a = ps[q]; b = pd[q]; }
    else         { a = ns[q-NPAIR]; b = nd[q-NPAIR]; }
    const float4* ra = (const float4*)(h3 + (size_t)a*160);
    const float4* rb = (const float4*)(h3 + (size_t)b*160);
    #pragma unroll
    for(int it = 0; it < 20; it++){
      int g = sub + it*2;            // interleaved k-groups
      float4 va = ra[g], vb = rb[g];
      int k = g*4;
      z[(k+0)*ZS + p] = va.x*vb.x;
      z[(k+1)*ZS + p] = va.y*vb.y;
      z[(k+2)*ZS + p] = va.z*vb.z;
      z[(k+3)*ZS + p] = va.w*vb.w;
    }
  }

  // --- stage 1: y1[64 pairs][80 cols] = leaky(z @ P1 + pb1) ---
  int tr = tid >> 3, tc = tid & 7;   // pairs tr*4..+3, cols tc*10..+9
  float acc1[4][10];
  #pragma unroll
  for(int j = 0; j < 10; j++){
    float bv = pb1[tc*10 + j];
    #pragma unroll
    for(int i = 0; i < 4; i++) acc1[i][j] = bv;
  }
  for(int k0 = 0; k0 < 160; k0 += 32){
    __syncthreads();                 // z ready / p1p free
    const float4* gp = (const float4*)(P1 + k0*80);
    for(int i = tid; i < 640; i += 128) ((float4*)p1p)[i] = gp[i];
    __syncthreads();
    #pragma unroll 4
    for(int kk = 0; kk < 32; kk++){
      float4 av = *(const float4*)&z[(k0+kk)*ZS + tr*4];
      const float* pc = &p1p[kk*80 + tc*10];
      float4 q0 = *(const float4*)pc;
      float4 q1 = *(const float4*)(pc+4);
      float2 q2 = *(const float2*)(pc+8);
      float az[4] = {av.x,av.y,av.z,av.w};
      float pbv[10] = {q0.x,q0.y,q0.z,q0.w,q1.x,q1.y,q1.z,q1.w,q2.x,q2.y};
      #pragma unroll
      for(int i = 0; i < 4; i++)
        #pragma unroll
        for(int j = 0; j < 10; j++)
          acc1[i][j] += az[i]*pbv[j];
    }
  }
  __syncthreads();                   // all z reads done; region reusable

  // y1^T [col][pair] via b128 (4 consecutive pairs per store); stage P2
  #pragma unroll
  for(int j = 0; j < 10; j++){
    int c = tc*10 + j;
    *(float4*)&y1[c*ZS + tr*4] = make_float4(
        leaky(acc1[0][j]), leaky(acc1[1][j]), leaky(acc1[2][j]), leaky(acc1[3][j]));
  }
  for(int i = tid; i < 800; i += 128) ((float4*)p2L)[i] = ((const float4*)P2)[i];
  __syncthreads();

  // --- stage 2+3 on wave 0 only: 4 pairs x 10 cols, fused dot with P3 ---
  if(tid < 64){
    int tr2 = tid >> 2, tc2 = tid & 3;   // pairs tr2*4..+3, cols tc2*10..+9
    float acc2[4][10];
    #pragma unroll
    for(int j = 0; j < 10; j++){
      float bv = pb2[tc2*10 + j];
      #pragma unroll
      for(int i = 0; i < 4; i++) acc2[i][j] = bv;
    }
    #pragma unroll 4
    for(int k = 0; k < 80; k++){
      float4 yv = *(const float4*)&y1[k*ZS + tr2*4];
      const float* pc = &p2L[k*40 + tc2*10];
      float2 r0 = *(const float2*)pc,     r1 = *(const float2*)(pc+2);
      float2 r2 = *(const float2*)(pc+4), r3 = *(const float2*)(pc+6);
      float2 r4 = *(const float2*)(pc+8);
      float ay[4] = {yv.x,yv.y,yv.z,yv.w};
      float pv[10] = {r0.x,r0.y,r1.x,r1.y,r2.x,r2.y,r3.x,r3.y,r4.x,r4.y};
      #pragma unroll
      for(int i = 0; i < 4; i++)
        #pragma unroll
        for(int j = 0; j < 10; j++)
          acc2[i][j] += ay[i]*pv[j];
    }
    float p3v[10];
    #pragma unroll
    for(int j = 0; j < 10; j++) p3v[j] = P3[tc2*10 + j];
    #pragma unroll
    for(int i = 0; i < 4; i++){
      float r = 0.f;
      #pragma unroll
      for(int j = 0; j < 10; j++) r += leaky(acc2[i][j])*p3v[j];
      r += __shfl_down(r, 2);
      r += __shfl_down(r, 1);
      if(tc2 == 0) out[pair0 + tr2*4 + i] = r + pb3[0];
    }
  }
}

// ---------------- launch ----------------

extern "C" void kernel_launch(void* const* d_in, const int* in_sizes, int n_in,
                              void* d_out, int out_size, void* d_ws, size_t ws_size,
                              hipStream_t stream) {
  const float* x  = (const float*)d_in[0];
  const float* w  = (const float*)d_in[1];
  const int* src  = (const int*)d_in[2];
  const int* dst  = (const int*)d_in[3];
  const int* ps   = (const int*)d_in[4];
  const int* pd   = (const int*)d_in[5];
  const int* ns   = (const int*)d_in[6];
  const int* nd   = (const int*)d_in[7];
  const float* W1 = (const float*)d_in[8];  const float* b1  = (const float*)d_in[9];
  const float* W2 = (const float*)d_in[10]; const float* b2  = (const float*)d_in[11];
  const float* W3 = (const float*)d_in[12]; const float* b3  = (const float*)d_in[13];
  const float* P1 = (const float*)d_in[14]; const float* pb1 = (const float*)d_in[15];
  const float* P2 = (const float*)d_in[16]; const float* pb2 = (const float*)d_in[17];
  const float* P3 = (const float*)d_in[18]; const float* pb3 = (const float*)d_in[19];
  float* out = (float*)d_out;

  char* p = (char*)d_ws;
  auto alloc = [&](size_t bytes)->char*{
    char* r = p; p += (bytes + 255) & ~(size_t)255; return r;
  };
  int*   cnt_out = (int*)  alloc(NN*4);          // these three must stay contiguous
  int*   cnt_in  = (int*)  alloc(NN*4);          // (zeroed with one memset)
  int*   fill    = (int*)  alloc(NN*4);
  int*   row_off = (int*)  alloc((NN+1)*4);
  float* out_nrm = (float*)alloc(NN*4);
  float* in_nrm  = (float*)alloc(NN*4);
  int*   es      = (int*)  alloc((size_t)EE*4);
  float* ew      = (float*)alloc((size_t)EE*4);
  float* bufA    = (float*)alloc((size_t)NN*512*4);  // h1 (N x 512)
  float* bufB    = (float*)alloc((size_t)NN*256*4);  // proj2 / proj3
  float* bufC    = (float*)alloc((size_t)NN*256*4);  // agg1 / h2

  size_t cntPad = (NN*4 + 255) & ~(size_t)255;
  hipMemsetAsync(cnt_out, 0, 3*cntPad, stream);

  degree_kernel<<<(EE+255)/256, 256, 0, stream>>>(src, dst, cnt_out, cnt_in);
  norm_kernel<<<(NN+255)/256, 256, 0, stream>>>(cnt_out, cnt_in, out_nrm, in_nrm);
  scan_kernel<<<1, 512, 0, stream>>>(cnt_in, row_off);
  bucket_kernel<<<(EE+255)/256, 256, 0, stream>>>(src, dst, w, out_nrm, row_off, fill, es, ew);

  dim3 gA(391, 4), gB(391, 2);

  // layer 1: agg(x, ew2) @ W1, epilogue relu(*in_norm + b1)
  agg_kernel<256,0><<<NN, 256, 0, stream>>>(x, es, ew, row_off, nullptr, nullptr, bufC);
  gemm_kernel<true><<<gA, 128, 0, stream>>>(bufC, W1, bufA, 256, 512, in_nrm, b1);

  // layer 2: agg(h1 @ W2, ew2), fused epilogue relu(*in_norm + b2)
  gemm_kernel<false><<<gB, 128, 0, stream>>>(bufA, W2, bufB, 512, 256, nullptr, nullptr);
  agg_kernel<256,1><<<NN, 256, 0, stream>>>(bufB, es, ew, row_off, in_nrm, b2, bufC);

  // layer 3: agg(h2 @ W3, ew2), fused epilogue *in_norm + b3 -> d_out h region
  gemm_kernel<false><<<gB, 128, 0, stream>>>(bufC, W3, bufB, 256, 160, nullptr, nullptr);
  agg_kernel<160,2><<<NN, 256, 0, stream>>>(bufB, es, ew, row_off, in_nrm, b3, out + 2*NPAIR);

  // predictor on pos+neg pairs
  predictor_kernel<<<(2*NPAIR)/64, 128, 0, stream>>>(out + 2*NPAIR, ps, pd, ns, nd,
                                                     P1, pb1, P2, pb2, P3, pb3, out);
}

// Round 7
// 1740.795 us; speedup vs baseline: 1.7847x; 1.0764x over previous
//
#include <hip/hip_runtime.h>
#include <math.h>

#define NN 50000
#define EE 800000
#define NPAIR 200000

__device__ __forceinline__ float leaky(float x){ return x >= 0.f ? x : 0.2f*x; }

// ---------------- degree / norms / CSR build ----------------

__global__ void degree_kernel(const int* __restrict__ src, const int* __restrict__ dst,
                              int* cnt_out, int* cnt_in){
  int i = blockIdx.x*blockDim.x + threadIdx.x;
  if(i < EE){
    atomicAdd(&cnt_out[src[i]], 1);
    atomicAdd(&cnt_in[dst[i]], 1);
  }
}

__global__ void norm_kernel(const int* __restrict__ cnt_out, const int* __restrict__ cnt_in,
                            float* __restrict__ out_norm, float* __restrict__ in_norm){
  int i = blockIdx.x*blockDim.x + threadIdx.x;
  if(i < NN){
    int o = cnt_out[i]; if(o < 1) o = 1;
    int d = cnt_in[i];  if(d < 1) d = 1;
    out_norm[i] = 1.f/sqrtf((float)o);
    in_norm[i]  = 1.f/sqrtf((float)d);
  }
}

// single-block exclusive scan of cnt_in[NN] -> row_off[NN+1]
__global__ void scan_kernel(const int* __restrict__ cnt, int* __restrict__ row_off){
  const int T = 512;
  __shared__ int sums[T];
  int t = threadIdx.x;
  int chunk = (NN + T - 1)/T;
  int base = t*chunk;
  int hi = base + chunk; if(hi > NN) hi = NN;
  int s = 0;
  for(int i = base; i < hi; i++) s += cnt[i];
  sums[t] = s;
  __syncthreads();
  for(int off = 1; off < T; off <<= 1){
    int add = (t >= off) ? sums[t-off] : 0;
    __syncthreads();
    sums[t] += add;
    __syncthreads();
  }
  int run = sums[t] - s;   // exclusive prefix of this thread's chunk
  for(int i = base; i < hi; i++){ row_off[i] = run; run += cnt[i]; }
  if(t == T-1) row_off[NN] = EE;
}

// ew2 = w * out_norm[src]: out_norm commutes with @W, folded into edge weight.
__global__ void bucket_kernel(const int* __restrict__ src, const int* __restrict__ dst,
                              const float* __restrict__ w, const float* __restrict__ out_norm,
                              const int* __restrict__ row_off,
                              int* fill, int* __restrict__ es, float* __restrict__ ew){
  int i = blockIdx.x*blockDim.x + threadIdx.x;
  if(i < EE){
    int d = dst[i];
    int s = src[i];
    int p = row_off[d] + atomicAdd(&fill[d], 1);
    es[p] = s;
    ew[p] = w[i] * out_norm[s];
  }
}

// ---------------- aggregation v2 (dst-CSR, float4, 4 edges in flight) ----------
// MODE 0: plain sum; MODE 1: relu(sum*in_norm[v] + bias); MODE 2: sum*in_norm[v]+bias
template<int F, int MODE>
__global__ __launch_bounds__(256) void agg_kernel(
    const float* __restrict__ feat, const int* __restrict__ es,
    const float* __restrict__ ew, const int* __restrict__ row_off,
    const float* __restrict__ innorm, const float* __restrict__ bias,
    float* __restrict__ out){
  constexpr int F4 = F/4;                 // 64 (F=256) or 40 (F=160)
  __shared__ float4 red[4*F4];
  int tid = threadIdx.x;
  int w = tid >> 6, lane = tid & 63;
  int v = blockIdx.x;
  int s = row_off[v], e = row_off[v+1];
  if(lane < F4){
    const float4* f4 = (const float4*)feat;
    float4 acc0 = {0,0,0,0}, acc1 = {0,0,0,0};
    int j = s + w;
    for(; j + 4 < e; j += 8){
      int u0 = es[j];   float w0 = ew[j];
      int u1 = es[j+4]; float w1 = ew[j+4];
      float4 a = f4[(size_t)u0*F4 + lane];
      float4 b = f4[(size_t)u1*F4 + lane];
      acc0.x += a.x*w0; acc0.y += a.y*w0; acc0.z += a.z*w0; acc0.w += a.w*w0;
      acc1.x += b.x*w1; acc1.y += b.y*w1; acc1.z += b.z*w1; acc1.w += b.w*w1;
    }
    if(j < e){
      int u = es[j]; float wt = ew[j];
      float4 a = f4[(size_t)u*F4 + lane];
      acc0.x += a.x*wt; acc0.y += a.y*wt; acc0.z += a.z*wt; acc0.w += a.w*wt;
    }
    acc0.x += acc1.x; acc0.y += acc1.y; acc0.z += acc1.z; acc0.w += acc1.w;
    red[w*F4 + lane] = acc0;
  }
  __syncthreads();
  if(tid < F4){
    float4 r0 = red[tid], r1 = red[F4+tid], r2 = red[2*F4+tid], r3 = red[3*F4+tid];
    float4 r;
    r.x = r0.x+r1.x+r2.x+r3.x;
    r.y = r0.y+r1.y+r2.y+r3.y;
    r.z = r0.z+r1.z+r2.z+r3.z;
    r.w = r0.w+r1.w+r2.w+r3.w;
    if(MODE >= 1){
      float inm = innorm[v];
      float4 bb = *(const float4*)&bias[tid*4];
      r.x = r.x*inm + bb.x; r.y = r.y*inm + bb.y;
      r.z = r.z*inm + bb.z; r.w = r.w*inm + bb.w;
      if(MODE == 1){
        r.x = fmaxf(r.x, 0.f); r.y = fmaxf(r.y, 0.f);
        r.z = fmaxf(r.z, 0.f); r.w = fmaxf(r.w, 0.f);
      }
    }
    ((float4*)(out + (size_t)v*F))[tid] = r;
  }
}

// ---------------- fp32 tiled GEMM v2 (R4 known-good): 128x128, 8x8 ----------
// 256 threads, no min-waves clamp (R3: (256,4) forced 64-VGPR cap -> spill).
// R6's 128-thread v3 regressed (~+210 us): 2-wave blocks can't hide latency.
template<bool EPI>
__global__ __launch_bounds__(256) void gemm_kernel(
    const float* __restrict__ A, const float* __restrict__ B, float* __restrict__ C,
    int K, int M, const float* __restrict__ innorm, const float* __restrict__ bias){
  __shared__ float As[16][132];   // [k][row], +4 pad
  __shared__ float Bs[16][128];   // [k][col]
  int tid = threadIdx.x;
  int row0 = blockIdx.x*128, col0 = blockIdx.y*128;
  int arow = tid >> 1, ak = (tid & 1)*8;
  int grow = row0 + arow;
  int bcol = (tid & 31)*4, brow = tid >> 5;
  int tr = tid >> 4, tc = tid & 15;
  float acc[8][8] = {};
  const float* Arow = A + (size_t)grow*K;
  bool bvalid = (col0 + bcol + 3 < M);

  for(int k0 = 0; k0 < K; k0 += 16){
    float4 av0 = {0,0,0,0}, av1 = {0,0,0,0};
    if(grow < NN){
      av0 = *(const float4*)&Arow[k0 + ak];
      av1 = *(const float4*)&Arow[k0 + ak + 4];
    }
    float4 bv0 = {0,0,0,0}, bv1 = {0,0,0,0};
    if(bvalid){
      bv0 = *(const float4*)&B[(size_t)(k0+brow)*M + col0 + bcol];
      bv1 = *(const float4*)&B[(size_t)(k0+brow+8)*M + col0 + bcol];
    }
    __syncthreads();   // previous iter's reads done before overwrite
    As[ak+0][arow] = av0.x; As[ak+1][arow] = av0.y;
    As[ak+2][arow] = av0.z; As[ak+3][arow] = av0.w;
    As[ak+4][arow] = av1.x; As[ak+5][arow] = av1.y;
    As[ak+6][arow] = av1.z; As[ak+7][arow] = av1.w;
    *(float4*)&Bs[brow][bcol]   = bv0;
    *(float4*)&Bs[brow+8][bcol] = bv1;
    __syncthreads();
    #pragma unroll
    for(int k = 0; k < 16; k++){
      float4 a0 = *(const float4*)&As[k][tr*8];
      float4 a1 = *(const float4*)&As[k][tr*8 + 4];
      float4 b0 = *(const float4*)&Bs[k][tc*8];
      float4 b1 = *(const float4*)&Bs[k][tc*8 + 4];
      float a[8] = {a0.x,a0.y,a0.z,a0.w,a1.x,a1.y,a1.z,a1.w};
      float b[8] = {b0.x,b0.y,b0.z,b0.w,b1.x,b1.y,b1.z,b1.w};
      #pragma unroll
      for(int i = 0; i < 8; i++)
        #pragma unroll
        for(int j = 0; j < 8; j++)
          acc[i][j] += a[i]*b[j];
    }
  }

  #pragma unroll
  for(int i = 0; i < 8; i++){
    int r = row0 + tr*8 + i;
    if(r >= NN) continue;
    float inm = EPI ? innorm[r] : 1.f;
    int c0 = col0 + tc*8;
    float vals[8];
    #pragma unroll
    for(int j = 0; j < 8; j++){
      float vv = acc[i][j];
      if(EPI){ vv = fmaxf(vv*inm + bias[c0 + j], 0.f); }
      vals[j] = vv;
    }
    if(col0 + 128 <= M){
      *(float4*)&C[(size_t)r*M + c0]     = make_float4(vals[0],vals[1],vals[2],vals[3]);
      *(float4*)&C[(size_t)r*M + c0 + 4] = make_float4(vals[4],vals[5],vals[6],vals[7]);
    }else{
      #pragma unroll
      for(int j = 0; j < 8; j++){
        int c = c0 + j;
        if(c < M) C[(size_t)r*M + c] = vals[j];
      }
    }
  }
}

// ---------------- predictor v5: 128 pairs/block, 256 threads, k-paneled z ----
// Keeps R4's proven occupancy (256 thr, 3 blocks/CU = 12 waves/CU; v4's 128-thr
// 6-wave version was latency-bound at 600 us) while halving LDS-cyc/pair-k via
// a 4p x 10c stage-1 microtile (z b128 + P 2xb128+b64 per wave-k).
// z is k-paneled [32][132] so phase-A LDS stays small; gather is partitioned
// across panels (same total bytes). Phase B: y1 [80][129] + P2 [80][40].
// LDS = max(4224+2560, 80*129+3200) floats = 13520 fl = 54080 B -> 3 blocks/CU.
#define Z_S 132   // 132 mod 32 = 4 -> 2-way max on z stores (free per m136)
#define Y_S 129   // +1 pad, conflict-free column access
__global__ __launch_bounds__(256) void predictor_kernel(
    const float* __restrict__ h3,
    const int* __restrict__ ps, const int* __restrict__ pd,
    const int* __restrict__ ns, const int* __restrict__ nd,
    const float* __restrict__ P1, const float* __restrict__ pb1,
    const float* __restrict__ P2, const float* __restrict__ pb2,
    const float* __restrict__ P3, const float* __restrict__ pb3,
    float* __restrict__ out){
  __shared__ float smem[13520];      // 54080 B
  float* z   = smem;                 // phase A: [32][Z_S] k-panel
  float* p1p = smem + 32*Z_S;        // phase A: [32][80] P1 k-panel
  float* y1  = smem;                 // phase B: [80][Y_S] (k-major, pair inner)
  float* p2L = smem + 80*Y_S;        // phase B: [80][40]
  int tid = threadIdx.x;
  int pair0 = blockIdx.x*128;        // grid = 400000/128 = 3125 exactly

  // pair gather setup: 2 threads per pair, each owns 16 k per panel
  int gp  = tid >> 1, half = tid & 1;
  int q = pair0 + gp;
  int a, b;
  if(q < NPAIR){ a = ps[q]; b = pd[q]; }
  else         { a = ns[q-NPAIR]; b = nd[q-NPAIR]; }
  const float4* ra = (const float4*)(h3 + (size_t)a*160);
  const float4* rb = (const float4*)(h3 + (size_t)b*160);

  // stage-1 microtile: pairs tr*4..+3, cols tc*10..+9
  int tr = tid >> 3, tc = tid & 7;
  float acc1[4][10];
  #pragma unroll
  for(int j = 0; j < 10; j++){
    float bv = pb1[tc*10 + j];
    #pragma unroll
    for(int i = 0; i < 4; i++) acc1[i][j] = bv;
  }

  for(int k0 = 0; k0 < 160; k0 += 32){
    __syncthreads();                 // previous panel's reads complete
    // gather this panel's z slice: z[k][p] = ha[k]*hb[k], k in [k0,k0+32)
    {
      const float4* ra4 = ra + (k0 >> 2) + half*4;
      const float4* rb4 = rb + (k0 >> 2) + half*4;
      #pragma unroll
      for(int i4 = 0; i4 < 4; i4++){
        float4 va = ra4[i4], vb = rb4[i4];
        int kl = half*16 + i4*4;
        z[(kl+0)*Z_S + gp] = va.x*vb.x;
        z[(kl+1)*Z_S + gp] = va.y*vb.y;
        z[(kl+2)*Z_S + gp] = va.z*vb.z;
        z[(kl+3)*Z_S + gp] = va.w*vb.w;
      }
    }
    // stage P1 panel [32][80]
    {
      const float4* gsrc = (const float4*)(P1 + k0*80);
      for(int i = tid; i < 640; i += 256) ((float4*)p1p)[i] = gsrc[i];
    }
    __syncthreads();
    #pragma unroll 4
    for(int kk = 0; kk < 32; kk++){
      float4 av = *(const float4*)&z[kk*Z_S + tr*4];
      const float* pc = &p1p[kk*80 + tc*10];
      float4 q0 = *(const float4*)pc;
      float4 q1 = *(const float4*)(pc+4);
      float2 q2 = *(const float2*)(pc+8);
      float az[4]  = {av.x,av.y,av.z,av.w};
      float pv[10] = {q0.x,q0.y,q0.z,q0.w,q1.x,q1.y,q1.z,q1.w,q2.x,q2.y};
      #pragma unroll
      for(int i = 0; i < 4; i++)
        #pragma unroll
        for(int j = 0; j < 10; j++)
          acc1[i][j] += az[i]*pv[j];
    }
  }
  __syncthreads();                   // all z/p1p reads done; region reused

  // y1[c][p] (b128 over 4 consecutive pairs); stage P2 [80][40]
  #pragma unroll
  for(int j = 0; j < 10; j++){
    int c = tc*10 + j;
    *(float4*)&y1[c*Y_S + tr*4] = make_float4(
        leaky(acc1[0][j]), leaky(acc1[1][j]), leaky(acc1[2][j]), leaky(acc1[3][j]));
  }
  for(int i = tid; i < 800; i += 256) ((float4*)p2L)[i] = ((const float4*)P2)[i];
  __syncthreads();

  // stage 2+3 on wave 0: 8 pairs x 10 cols per thread, fused P3 dot
  if(tid < 64){
    int tr2 = tid >> 2, tc2 = tid & 3;   // pairs tr2*8..+7, cols tc2*10..+9
    float acc2[8][10];
    #pragma unroll
    for(int j = 0; j < 10; j++){
      float bv = pb2[tc2*10 + j];
      #pragma unroll
      for(int i = 0; i < 8; i++) acc2[i][j] = bv;
    }
    #pragma unroll 4
    for(int k = 0; k < 80; k++){
      float4 y0 = *(const float4*)&y1[k*Y_S + tr2*8];
      float4 y4 = *(const float4*)&y1[k*Y_S + tr2*8 + 4];
      const float* pc = &p2L[k*40 + tc2*10];
      float4 q0 = *(const float4*)pc;
      float4 q1 = *(const float4*)(pc+4);
      float2 q2 = *(const float2*)(pc+8);
      float ay[8]  = {y0.x,y0.y,y0.z,y0.w,y4.x,y4.y,y4.z,y4.w};
      float pv[10] = {q0.x,q0.y,q0.z,q0.w,q1.x,q1.y,q1.z,q1.w,q2.x,q2.y};
      #pragma unroll
      for(int i = 0; i < 8; i++)
        #pragma unroll
        for(int j = 0; j < 10; j++)
          acc2[i][j] += ay[i]*pv[j];
    }
    float p3v[10];
    #pragma unroll
    for(int j = 0; j < 10; j++) p3v[j] = P3[tc2*10 + j];
    #pragma unroll
    for(int i = 0; i < 8; i++){
      float r = 0.f;
      #pragma unroll
      for(int j = 0; j < 10; j++) r += leaky(acc2[i][j])*p3v[j];
      r += __shfl_down(r, 2);
      r += __shfl_down(r, 1);
      if(tc2 == 0) out[pair0 + tr2*8 + i] = r + pb3[0];
    }
  }
}

// ---------------- launch ----------------

extern "C" void kernel_launch(void* const* d_in, const int* in_sizes, int n_in,
                              void* d_out, int out_size, void* d_ws, size_t ws_size,
                              hipStream_t stream) {
  const float* x  = (const float*)d_in[0];
  const float* w  = (const float*)d_in[1];
  const int* src  = (const int*)d_in[2];
  const int* dst  = (const int*)d_in[3];
  const int* ps   = (const int*)d_in[4];
  const int* pd   = (const int*)d_in[5];
  const int* ns   = (const int*)d_in[6];
  const int* nd   = (const int*)d_in[7];
  const float* W1 = (const float*)d_in[8];  const float* b1  = (const float*)d_in[9];
  const float* W2 = (const float*)d_in[10]; const float* b2  = (const float*)d_in[11];
  const float* W3 = (const float*)d_in[12]; const float* b3  = (const float*)d_in[13];
  const float* P1 = (const float*)d_in[14]; const float* pb1 = (const float*)d_in[15];
  const float* P2 = (const float*)d_in[16]; const float* pb2 = (const float*)d_in[17];
  const float* P3 = (const float*)d_in[18]; const float* pb3 = (const float*)d_in[19];
  float* out = (float*)d_out;

  char* p = (char*)d_ws;
  auto alloc = [&](size_t bytes)->char*{
    char* r = p; p += (bytes + 255) & ~(size_t)255; return r;
  };
  int*   cnt_out = (int*)  alloc(NN*4);          // these three must stay contiguous
  int*   cnt_in  = (int*)  alloc(NN*4);          // (zeroed with one memset)
  int*   fill    = (int*)  alloc(NN*4);
  int*   row_off = (int*)  alloc((NN+1)*4);
  float* out_nrm = (float*)alloc(NN*4);
  float* in_nrm  = (float*)alloc(NN*4);
  int*   es      = (int*)  alloc((size_t)EE*4);
  float* ew      = (float*)alloc((size_t)EE*4);
  float* bufA    = (float*)alloc((size_t)NN*512*4);  // h1 (N x 512)
  float* bufB    = (float*)alloc((size_t)NN*256*4);  // proj2 / proj3
  float* bufC    = (float*)alloc((size_t)NN*256*4);  // agg1 / h2

  size_t cntPad = (NN*4 + 255) & ~(size_t)255;
  hipMemsetAsync(cnt_out, 0, 3*cntPad, stream);

  degree_kernel<<<(EE+255)/256, 256, 0, stream>>>(src, dst, cnt_out, cnt_in);
  norm_kernel<<<(NN+255)/256, 256, 0, stream>>>(cnt_out, cnt_in, out_nrm, in_nrm);
  scan_kernel<<<1, 512, 0, stream>>>(cnt_in, row_off);
  bucket_kernel<<<(EE+255)/256, 256, 0, stream>>>(src, dst, w, out_nrm, row_off, fill, es, ew);

  dim3 gA(391, 4), gB(391, 2);

  // layer 1: agg(x, ew2) @ W1, epilogue relu(*in_norm + b1)
  agg_kernel<256,0><<<NN, 256, 0, stream>>>(x, es, ew, row_off, nullptr, nullptr, bufC);
  gemm_kernel<true><<<gA, 256, 0, stream>>>(bufC, W1, bufA, 256, 512, in_nrm, b1);

  // layer 2: agg(h1 @ W2, ew2), fused epilogue relu(*in_norm + b2)
  gemm_kernel<false><<<gB, 256, 0, stream>>>(bufA, W2, bufB, 512, 256, nullptr, nullptr);
  agg_kernel<256,1><<<NN, 256, 0, stream>>>(bufB, es, ew, row_off, in_nrm, b2, bufC);

  // layer 3: agg(h2 @ W3, ew2), fused epilogue *in_norm + b3 -> d_out h region
  gemm_kernel<false><<<gB, 256, 0, stream>>>(bufC, W3, bufB, 256, 160, nullptr, nullptr);
  agg_kernel<160,2><<<NN, 256, 0, stream>>>(bufB, es, ew, row_off, in_nrm, b3, out + 2*NPAIR);

  // predictor on pos+neg pairs
  predictor_kernel<<<(2*NPAIR)/128, 256, 0, stream>>>(out + 2*NPAIR, ps, pd, ns, nd,
                                                      P1, pb1, P2, pb2, P3, pb3, out);
}

// Round 8
// 1297.092 us; speedup vs baseline: 2.3952x; 1.3421x over previous
//
#include <hip/hip_runtime.h>
#include <math.h>

#define NN 50000
#define EE 800000
#define NPAIR 200000

__device__ __forceinline__ float leaky(float x){ return x >= 0.f ? x : 0.2f*x; }

// ---------------- degree / norms / CSR build ----------------

__global__ void degree_kernel(const int* __restrict__ src, const int* __restrict__ dst,
                              int* cnt_out, int* cnt_in){
  int i = blockIdx.x*blockDim.x + threadIdx.x;
  if(i < EE){
    atomicAdd(&cnt_out[src[i]], 1);
    atomicAdd(&cnt_in[dst[i]], 1);
  }
}

__global__ void norm_kernel(const int* __restrict__ cnt_out, const int* __restrict__ cnt_in,
                            float* __restrict__ out_norm, float* __restrict__ in_norm){
  int i = blockIdx.x*blockDim.x + threadIdx.x;
  if(i < NN){
    int o = cnt_out[i]; if(o < 1) o = 1;
    int d = cnt_in[i];  if(d < 1) d = 1;
    out_norm[i] = 1.f/sqrtf((float)o);
    in_norm[i]  = 1.f/sqrtf((float)d);
  }
}

// single-block exclusive scan of cnt_in[NN] -> row_off[NN+1]
__global__ void scan_kernel(const int* __restrict__ cnt, int* __restrict__ row_off){
  const int T = 512;
  __shared__ int sums[T];
  int t = threadIdx.x;
  int chunk = (NN + T - 1)/T;
  int base = t*chunk;
  int hi = base + chunk; if(hi > NN) hi = NN;
  int s = 0;
  for(int i = base; i < hi; i++) s += cnt[i];
  sums[t] = s;
  __syncthreads();
  for(int off = 1; off < T; off <<= 1){
    int add = (t >= off) ? sums[t-off] : 0;
    __syncthreads();
    sums[t] += add;
    __syncthreads();
  }
  int run = sums[t] - s;   // exclusive prefix of this thread's chunk
  for(int i = base; i < hi; i++){ row_off[i] = run; run += cnt[i]; }
  if(t == T-1) row_off[NN] = EE;
}

// ew2 = w * out_norm[src]: out_norm commutes with @W, folded into edge weight.
__global__ void bucket_kernel(const int* __restrict__ src, const int* __restrict__ dst,
                              const float* __restrict__ w, const float* __restrict__ out_norm,
                              const int* __restrict__ row_off,
                              int* fill, int* __restrict__ es, float* __restrict__ ew){
  int i = blockIdx.x*blockDim.x + threadIdx.x;
  if(i < EE){
    int d = dst[i];
    int s = src[i];
    int p = row_off[d] + atomicAdd(&fill[d], 1);
    es[p] = s;
    ew[p] = w[i] * out_norm[s];
  }
}

// ---------------- aggregation v3: one WAVE per node, no LDS, no barrier ------
// 4 nodes per 256-thread block; 4 gather rows in flight per wave (unroll 4).
// MODE 0: plain sum; MODE 1: relu(sum*in_norm[v]+bias); MODE 2: sum*in_norm[v]+bias
template<int F, int MODE>
__global__ __launch_bounds__(256) void agg_kernel(
    const float* __restrict__ feat, const int* __restrict__ es,
    const float* __restrict__ ew, const int* __restrict__ row_off,
    const float* __restrict__ innorm, const float* __restrict__ bias,
    float* __restrict__ out){
  constexpr int F4 = F/4;                 // 64 (F=256) or 40 (F=160)
  int wid = threadIdx.x >> 6, lane = threadIdx.x & 63;
  int v = blockIdx.x*4 + wid;
  if(v >= NN || lane >= F4) return;
  int s = row_off[v], e = row_off[v+1];
  const float4* f4 = (const float4*)feat;
  float4 a0 = {0,0,0,0}, a1 = {0,0,0,0}, a2 = {0,0,0,0}, a3 = {0,0,0,0};
  int j = s;
  for(; j + 3 < e; j += 4){
    int   i0 = es[j],   i1 = es[j+1], i2 = es[j+2], i3 = es[j+3];
    float w0 = ew[j],   w1 = ew[j+1], w2 = ew[j+2], w3 = ew[j+3];
    float4 r0 = f4[(size_t)i0*F4 + lane];
    float4 r1 = f4[(size_t)i1*F4 + lane];
    float4 r2 = f4[(size_t)i2*F4 + lane];
    float4 r3 = f4[(size_t)i3*F4 + lane];
    a0.x += r0.x*w0; a0.y += r0.y*w0; a0.z += r0.z*w0; a0.w += r0.w*w0;
    a1.x += r1.x*w1; a1.y += r1.y*w1; a1.z += r1.z*w1; a1.w += r1.w*w1;
    a2.x += r2.x*w2; a2.y += r2.y*w2; a2.z += r2.z*w2; a2.w += r2.w*w2;
    a3.x += r3.x*w3; a3.y += r3.y*w3; a3.z += r3.z*w3; a3.w += r3.w*w3;
  }
  for(; j < e; j++){
    int idx = es[j]; float wt = ew[j];
    float4 r = f4[(size_t)idx*F4 + lane];
    a0.x += r.x*wt; a0.y += r.y*wt; a0.z += r.z*wt; a0.w += r.w*wt;
  }
  float4 r;
  r.x = (a0.x+a1.x)+(a2.x+a3.x);
  r.y = (a0.y+a1.y)+(a2.y+a3.y);
  r.z = (a0.z+a1.z)+(a2.z+a3.z);
  r.w = (a0.w+a1.w)+(a2.w+a3.w);
  if(MODE >= 1){
    float inm = innorm[v];
    float4 bb = *(const float4*)&bias[lane*4];
    r.x = r.x*inm + bb.x; r.y = r.y*inm + bb.y;
    r.z = r.z*inm + bb.z; r.w = r.w*inm + bb.w;
    if(MODE == 1){
      r.x = fmaxf(r.x, 0.f); r.y = fmaxf(r.y, 0.f);
      r.z = fmaxf(r.z, 0.f); r.w = fmaxf(r.w, 0.f);
    }
  }
  ((float4*)(out + (size_t)v*F))[lane] = r;
}

// ---------------- fp32 tiled GEMM v2 (R4 known-good): 128x128, 8x8 ----------
// 256 threads, no min-waves clamp (R3: (256,4) forced 64-VGPR cap -> spill).
// R6's 128-thread v3 regressed (~+210 us): 2-wave blocks can't hide latency.
template<bool EPI>
__global__ __launch_bounds__(256) void gemm_kernel(
    const float* __restrict__ A, const float* __restrict__ B, float* __restrict__ C,
    int K, int M, const float* __restrict__ innorm, const float* __restrict__ bias){
  __shared__ float As[16][132];   // [k][row], +4 pad
  __shared__ float Bs[16][128];   // [k][col]
  int tid = threadIdx.x;
  int row0 = blockIdx.x*128, col0 = blockIdx.y*128;
  int arow = tid >> 1, ak = (tid & 1)*8;
  int grow = row0 + arow;
  int bcol = (tid & 31)*4, brow = tid >> 5;
  int tr = tid >> 4, tc = tid & 15;
  float acc[8][8] = {};
  const float* Arow = A + (size_t)grow*K;
  bool bvalid = (col0 + bcol + 3 < M);

  for(int k0 = 0; k0 < K; k0 += 16){
    float4 av0 = {0,0,0,0}, av1 = {0,0,0,0};
    if(grow < NN){
      av0 = *(const float4*)&Arow[k0 + ak];
      av1 = *(const float4*)&Arow[k0 + ak + 4];
    }
    float4 bv0 = {0,0,0,0}, bv1 = {0,0,0,0};
    if(bvalid){
      bv0 = *(const float4*)&B[(size_t)(k0+brow)*M + col0 + bcol];
      bv1 = *(const float4*)&B[(size_t)(k0+brow+8)*M + col0 + bcol];
    }
    __syncthreads();   // previous iter's reads done before overwrite
    As[ak+0][arow] = av0.x; As[ak+1][arow] = av0.y;
    As[ak+2][arow] = av0.z; As[ak+3][arow] = av0.w;
    As[ak+4][arow] = av1.x; As[ak+5][arow] = av1.y;
    As[ak+6][arow] = av1.z; As[ak+7][arow] = av1.w;
    *(float4*)&Bs[brow][bcol]   = bv0;
    *(float4*)&Bs[brow+8][bcol] = bv1;
    __syncthreads();
    #pragma unroll
    for(int k = 0; k < 16; k++){
      float4 a0 = *(const float4*)&As[k][tr*8];
      float4 a1 = *(const float4*)&As[k][tr*8 + 4];
      float4 b0 = *(const float4*)&Bs[k][tc*8];
      float4 b1 = *(const float4*)&Bs[k][tc*8 + 4];
      float a[8] = {a0.x,a0.y,a0.z,a0.w,a1.x,a1.y,a1.z,a1.w};
      float b[8] = {b0.x,b0.y,b0.z,b0.w,b1.x,b1.y,b1.z,b1.w};
      #pragma unroll
      for(int i = 0; i < 8; i++)
        #pragma unroll
        for(int j = 0; j < 8; j++)
          acc[i][j] += a[i]*b[j];
    }
  }

  #pragma unroll
  for(int i = 0; i < 8; i++){
    int r = row0 + tr*8 + i;
    if(r >= NN) continue;
    float inm = EPI ? innorm[r] : 1.f;
    int c0 = col0 + tc*8;
    float vals[8];
    #pragma unroll
    for(int j = 0; j < 8; j++){
      float vv = acc[i][j];
      if(EPI){ vv = fmaxf(vv*inm + bias[c0 + j], 0.f); }
      vals[j] = vv;
    }
    if(col0 + 128 <= M){
      *(float4*)&C[(size_t)r*M + c0]     = make_float4(vals[0],vals[1],vals[2],vals[3]);
      *(float4*)&C[(size_t)r*M + c0 + 4] = make_float4(vals[4],vals[5],vals[6],vals[7]);
    }else{
      #pragma unroll
      for(int j = 0; j < 8; j++){
        int c = c0 + j;
        if(c < M) C[(size_t)r*M + c] = vals[j];
      }
    }
  }
}

// ---------------- predictor (R4-exact, benched 257 us): 64 pairs/block -------
// 256 threads, LDS 53760 B -> 3 blocks/CU = 12 waves/CU. z gathered ONCE
// upfront (deep MLP, one wait); only the small P1 panels sit behind barriers.
// R5/R6/R7 restructures all regressed — do not touch this kernel.
#define ZS 68   // 68 mod 32 = 4 -> stores 2-way max (free); 272B rows keep b128 align
__global__ __launch_bounds__(256) void predictor_kernel(
    const float* __restrict__ h3, const int* __restrict__ ps, const int* __restrict__ pd,
    const int* __restrict__ ns, const int* __restrict__ nd,
    const float* __restrict__ P1, const float* __restrict__ pb1,
    const float* __restrict__ P2, const float* __restrict__ pb2,
    const float* __restrict__ P3, const float* __restrict__ pb3,
    float* __restrict__ out){
  __shared__ float smem[13440];
  float* z   = smem;            // [160][ZS]
  float* p1p = smem + 160*ZS;   // [32][80]
  float* y1  = smem;            // [80][65]
  float* p2  = smem + 5200;     // [80][40]
  float* y2  = smem + 8400;     // [40][65]
  int tid = threadIdx.x;
  int pair0 = blockIdx.x*64;    // grid = 2*NPAIR/64 exactly

  // --- gather h3 rows, z[k][p] = ha[k]*hb[k] (transposed, conflict-free) ---
  {
    int p = tid >> 2, sub = tid & 3;
    int q = pair0 + p;
    int a, b;
    if(q < NPAIR){ a = ps[q]; b = pd[q]; }
    else         { a = ns[q-NPAIR]; b = nd[q-NPAIR]; }
    const float4* ra = (const float4*)(h3 + (size_t)a*160);
    const float4* rb = (const float4*)(h3 + (size_t)b*160);
    #pragma unroll
    for(int it = 0; it < 10; it++){
      int g = sub + it*4;            // interleaved k-groups: banks 2-way max
      float4 va = ra[g], vb = rb[g];
      int k = g*4;
      z[(k+0)*ZS + p] = va.x*vb.x;
      z[(k+1)*ZS + p] = va.y*vb.y;
      z[(k+2)*ZS + p] = va.z*vb.z;
      z[(k+3)*ZS + p] = va.w*vb.w;
    }
  }

  // --- stage 1: y1[64 pairs][80 cols] = leaky(z @ P1 + pb1) ---
  int tr = tid >> 4, tc = tid & 15;       // thread: pairs tr*4..+3, cols tc+16j
  float acc1[4][5];
  #pragma unroll
  for(int j = 0; j < 5; j++){
    float bv = pb1[tc + 16*j];
    #pragma unroll
    for(int i = 0; i < 4; i++) acc1[i][j] = bv;
  }
  for(int k0 = 0; k0 < 160; k0 += 32){
    __syncthreads();                       // z ready / p1p free
    const float4* gp = (const float4*)(P1 + k0*80);
    for(int i = tid; i < 640; i += 256) ((float4*)p1p)[i] = gp[i];
    __syncthreads();
    #pragma unroll 8
    for(int kk = 0; kk < 32; kk++){
      float4 av = *(const float4*)&z[(k0+kk)*ZS + tr*4];
      float a0 = av.x, a1 = av.y, a2 = av.z, a3 = av.w;
      float b[5];
      #pragma unroll
      for(int j = 0; j < 5; j++) b[j] = p1p[kk*80 + tc + 16*j];
      #pragma unroll
      for(int j = 0; j < 5; j++){
        acc1[0][j] += a0*b[j];
        acc1[1][j] += a1*b[j];
        acc1[2][j] += a2*b[j];
        acc1[3][j] += a3*b[j];
      }
    }
  }
  __syncthreads();                          // all z reads done; region reusable

  // write y1^T (padded 65), stage P2
  #pragma unroll
  for(int i = 0; i < 4; i++)
    #pragma unroll
    for(int j = 0; j < 5; j++)
      y1[(tc + 16*j)*65 + tr*4 + i] = leaky(acc1[i][j]);
  for(int i = tid; i < 800; i += 256) ((float4*)p2)[i] = ((const float4*)P2)[i];
  __syncthreads();

  // --- stage 2: y2[64][40] = leaky(y1 @ P2 + pb2); thread: 2 pairs x 5 cols ---
  int tr2 = tid >> 3, tc2 = tid & 7;       // pairs tr2*2..+1, cols tc2+8j
  float acc2[2][5];
  #pragma unroll
  for(int j = 0; j < 5; j++){
    float bv = pb2[tc2 + 8*j];
    acc2[0][j] = bv; acc2[1][j] = bv;
  }
  #pragma unroll 4
  for(int k = 0; k < 80; k++){
    float a0 = y1[k*65 + tr2*2], a1 = y1[k*65 + tr2*2 + 1];
    #pragma unroll
    for(int j = 0; j < 5; j++){
      float bv = p2[k*40 + tc2 + 8*j];
      acc2[0][j] += a0*bv;
      acc2[1][j] += a1*bv;
    }
  }
  #pragma unroll
  for(int i = 0; i < 2; i++)
    #pragma unroll
    for(int j = 0; j < 5; j++)
      y2[(tc2 + 8*j)*65 + tr2*2 + i] = leaky(acc2[i][j]);
  __syncthreads();

  // --- stage 3: out[p] = y2[p] . P3 + pb3 ---
  if(tid < 64){
    float s = pb3[0];
    #pragma unroll 8
    for(int k = 0; k < 40; k++) s += y2[k*65 + tid]*P3[k];
    out[pair0 + tid] = s;
  }
}

// ---------------- launch ----------------

extern "C" void kernel_launch(void* const* d_in, const int* in_sizes, int n_in,
                              void* d_out, int out_size, void* d_ws, size_t ws_size,
                              hipStream_t stream) {
  const float* x  = (const float*)d_in[0];
  const float* w  = (const float*)d_in[1];
  const int* src  = (const int*)d_in[2];
  const int* dst  = (const int*)d_in[3];
  const int* ps   = (const int*)d_in[4];
  const int* pd   = (const int*)d_in[5];
  const int* ns   = (const int*)d_in[6];
  const int* nd   = (const int*)d_in[7];
  const float* W1 = (const float*)d_in[8];  const float* b1  = (const float*)d_in[9];
  const float* W2 = (const float*)d_in[10]; const float* b2  = (const float*)d_in[11];
  const float* W3 = (const float*)d_in[12]; const float* b3  = (const float*)d_in[13];
  const float* P1 = (const float*)d_in[14]; const float* pb1 = (const float*)d_in[15];
  const float* P2 = (const float*)d_in[16]; const float* pb2 = (const float*)d_in[17];
  const float* P3 = (const float*)d_in[18]; const float* pb3 = (const float*)d_in[19];
  float* out = (float*)d_out;

  char* p = (char*)d_ws;
  auto alloc = [&](size_t bytes)->char*{
    char* r = p; p += (bytes + 255) & ~(size_t)255; return r;
  };
  int*   cnt_out = (int*)  alloc(NN*4);          // these three must stay contiguous
  int*   cnt_in  = (int*)  alloc(NN*4);          // (zeroed with one memset)
  int*   fill    = (int*)  alloc(NN*4);
  int*   row_off = (int*)  alloc((NN+1)*4);
  float* out_nrm = (float*)alloc(NN*4);
  float* in_nrm  = (float*)alloc(NN*4);
  int*   es      = (int*)  alloc((size_t)EE*4);
  float* ew      = (float*)alloc((size_t)EE*4);
  float* bufA    = (float*)alloc((size_t)NN*512*4);  // h1 (N x 512)
  float* bufB    = (float*)alloc((size_t)NN*256*4);  // proj2 / proj3
  float* bufC    = (float*)alloc((size_t)NN*256*4);  // agg1 / h2

  size_t cntPad = (NN*4 + 255) & ~(size_t)255;
  hipMemsetAsync(cnt_out, 0, 3*cntPad, stream);

  degree_kernel<<<(EE+255)/256, 256, 0, stream>>>(src, dst, cnt_out, cnt_in);
  norm_kernel<<<(NN+255)/256, 256, 0, stream>>>(cnt_out, cnt_in, out_nrm, in_nrm);
  scan_kernel<<<1, 512, 0, stream>>>(cnt_in, row_off);
  bucket_kernel<<<(EE+255)/256, 256, 0, stream>>>(src, dst, w, out_nrm, row_off, fill, es, ew);

  dim3 gA(391, 4), gB(391, 2);
  int aggGrid = (NN + 3)/4;   // 4 nodes (waves) per block

  // layer 1: agg(x, ew2) @ W1, epilogue relu(*in_norm + b1)
  agg_kernel<256,0><<<aggGrid, 256, 0, stream>>>(x, es, ew, row_off, nullptr, nullptr, bufC);
  gemm_kernel<true><<<gA, 256, 0, stream>>>(bufC, W1, bufA, 256, 512, in_nrm, b1);

  // layer 2: agg(h1 @ W2, ew2), fused epilogue relu(*in_norm + b2)
  gemm_kernel<false><<<gB, 256, 0, stream>>>(bufA, W2, bufB, 512, 256, nullptr, nullptr);
  agg_kernel<256,1><<<aggGrid, 256, 0, stream>>>(bufB, es, ew, row_off, in_nrm, b2, bufC);

  // layer 3: agg(h2 @ W3, ew2), fused epilogue *in_norm + b3 -> d_out h region
  gemm_kernel<false><<<gB, 256, 0, stream>>>(bufC, W3, bufB, 256, 160, nullptr, nullptr);
  agg_kernel<160,2><<<aggGrid, 256, 0, stream>>>(bufB, es, ew, row_off, in_nrm, b3, out + 2*NPAIR);

  // predictor on pos+neg pairs
  predictor_kernel<<<(2*NPAIR)/64, 256, 0, stream>>>(out + 2*NPAIR, ps, pd, ns, nd,
                                                     P1, pb1, P2, pb2, P3, pb3, out);
}

// Round 9
// 1041.997 us; speedup vs baseline: 2.9815x; 1.2448x over previous
//
#include <hip/hip_runtime.h>
#include <math.h>

#define NN 50000
#define EE 800000
#define NPAIR 200000

typedef unsigned short u16;
typedef short short8v __attribute__((ext_vector_type(8)));
typedef float float16v __attribute__((ext_vector_type(16)));

__device__ __forceinline__ float leaky(float x){ return x >= 0.f ? x : 0.2f*x; }

// bf16 round-to-nearest-even helpers for the hi/lo split
__device__ __forceinline__ u16 bfhi(float x){
  union{float f; unsigned u;} v; v.f = x;
  unsigned r = (v.u + 0x7FFFu + ((v.u >> 16) & 1u)) >> 16;
  return (u16)r;
}
__device__ __forceinline__ float bf2f(u16 h){
  union{unsigned u; float f;} v; v.u = ((unsigned)h) << 16; return v.f;
}
__device__ __forceinline__ void split2(float x, float y, unsigned &hp, unsigned &lp){
  u16 hx = bfhi(x), hy = bfhi(y);
  u16 lx = bfhi(x - bf2f(hx)), ly = bfhi(y - bf2f(hy));
  hp = (unsigned)hx | ((unsigned)hy << 16);
  lp = (unsigned)lx | ((unsigned)ly << 16);
}

// ---------------- degree / norms / CSR build ----------------

__global__ void degree_kernel(const int* __restrict__ src, const int* __restrict__ dst,
                              int* cnt_out, int* cnt_in){
  int i = blockIdx.x*blockDim.x + threadIdx.x;
  if(i < EE){
    atomicAdd(&cnt_out[src[i]], 1);
    atomicAdd(&cnt_in[dst[i]], 1);
  }
}

__global__ void norm_kernel(const int* __restrict__ cnt_out, const int* __restrict__ cnt_in,
                            float* __restrict__ out_norm, float* __restrict__ in_norm){
  int i = blockIdx.x*blockDim.x + threadIdx.x;
  if(i < NN){
    int o = cnt_out[i]; if(o < 1) o = 1;
    int d = cnt_in[i];  if(d < 1) d = 1;
    out_norm[i] = 1.f/sqrtf((float)o);
    in_norm[i]  = 1.f/sqrtf((float)d);
  }
}

// single-block exclusive scan of cnt_in[NN] -> row_off[NN+1]
__global__ void scan_kernel(const int* __restrict__ cnt, int* __restrict__ row_off){
  const int T = 512;
  __shared__ int sums[T];
  int t = threadIdx.x;
  int chunk = (NN + T - 1)/T;
  int base = t*chunk;
  int hi = base + chunk; if(hi > NN) hi = NN;
  int s = 0;
  for(int i = base; i < hi; i++) s += cnt[i];
  sums[t] = s;
  __syncthreads();
  for(int off = 1; off < T; off <<= 1){
    int add = (t >= off) ? sums[t-off] : 0;
    __syncthreads();
    sums[t] += add;
    __syncthreads();
  }
  int run = sums[t] - s;
  for(int i = base; i < hi; i++){ row_off[i] = run; run += cnt[i]; }
  if(t == T-1) row_off[NN] = EE;
}

// ew2 = w * out_norm[src]: out_norm commutes with @W, folded into edge weight.
__global__ void bucket_kernel(const int* __restrict__ src, const int* __restrict__ dst,
                              const float* __restrict__ w, const float* __restrict__ out_norm,
                              const int* __restrict__ row_off,
                              int* fill, int* __restrict__ es, float* __restrict__ ew){
  int i = blockIdx.x*blockDim.x + threadIdx.x;
  if(i < EE){
    int d = dst[i];
    int s = src[i];
    int p = row_off[d] + atomicAdd(&fill[d], 1);
    es[p] = s;
    ew[p] = w[i] * out_norm[s];
  }
}

// W (K x M fp32, row-major) -> Wt_hi / Wt_lo (M x K bf16): transposed so the
// GEMM can stage B-operand columns with contiguous-k vector loads.
__global__ void wsplit_kernel(const float* __restrict__ W, int K, int M,
                              u16* __restrict__ Whi, u16* __restrict__ Wlo){
  int i = blockIdx.x*256 + threadIdx.x;     // i = m*K + k
  if(i < K*M){
    int m = i / K, k = i - m*K;
    float a = W[(size_t)k*M + m];
    u16 h = bfhi(a);
    Whi[i] = h;
    Wlo[i] = bfhi(a - bf2f(h));
  }
}

// ---------------- aggregation v3: one WAVE per node (R8, proven) -------------
template<int F, int MODE>
__global__ __launch_bounds__(256) void agg_kernel(
    const float* __restrict__ feat, const int* __restrict__ es,
    const float* __restrict__ ew, const int* __restrict__ row_off,
    const float* __restrict__ innorm, const float* __restrict__ bias,
    float* __restrict__ out){
  constexpr int F4 = F/4;
  int wid = threadIdx.x >> 6, lane = threadIdx.x & 63;
  int v = blockIdx.x*4 + wid;
  if(v >= NN || lane >= F4) return;
  int s = row_off[v], e = row_off[v+1];
  const float4* f4 = (const float4*)feat;
  float4 a0 = {0,0,0,0}, a1 = {0,0,0,0}, a2 = {0,0,0,0}, a3 = {0,0,0,0};
  int j = s;
  for(; j + 3 < e; j += 4){
    int   i0 = es[j],   i1 = es[j+1], i2 = es[j+2], i3 = es[j+3];
    float w0 = ew[j],   w1 = ew[j+1], w2 = ew[j+2], w3 = ew[j+3];
    float4 r0 = f4[(size_t)i0*F4 + lane];
    float4 r1 = f4[(size_t)i1*F4 + lane];
    float4 r2 = f4[(size_t)i2*F4 + lane];
    float4 r3 = f4[(size_t)i3*F4 + lane];
    a0.x += r0.x*w0; a0.y += r0.y*w0; a0.z += r0.z*w0; a0.w += r0.w*w0;
    a1.x += r1.x*w1; a1.y += r1.y*w1; a1.z += r1.z*w1; a1.w += r1.w*w1;
    a2.x += r2.x*w2; a2.y += r2.y*w2; a2.z += r2.z*w2; a2.w += r2.w*w2;
    a3.x += r3.x*w3; a3.y += r3.y*w3; a3.z += r3.z*w3; a3.w += r3.w*w3;
  }
  for(; j < e; j++){
    int idx = es[j]; float wt = ew[j];
    float4 r = f4[(size_t)idx*F4 + lane];
    a0.x += r.x*wt; a0.y += r.y*wt; a0.z += r.z*wt; a0.w += r.w*wt;
  }
  float4 r;
  r.x = (a0.x+a1.x)+(a2.x+a3.x);
  r.y = (a0.y+a1.y)+(a2.y+a3.y);
  r.z = (a0.z+a1.z)+(a2.z+a3.z);
  r.w = (a0.w+a1.w)+(a2.w+a3.w);
  if(MODE >= 1){
    float inm = innorm[v];
    float4 bb = *(const float4*)&bias[lane*4];
    r.x = r.x*inm + bb.x; r.y = r.y*inm + bb.y;
    r.z = r.z*inm + bb.z; r.w = r.w*inm + bb.w;
    if(MODE == 1){
      r.x = fmaxf(r.x, 0.f); r.y = fmaxf(r.y, 0.f);
      r.z = fmaxf(r.z, 0.f); r.w = fmaxf(r.w, 0.f);
    }
  }
  ((float4*)(out + (size_t)v*F))[lane] = r;
}

// ---------------- GEMM via MFMA bf16x2-split (3 passes) ----------------------
// C = A @ B with A fp32 split on the fly, B pre-split (wsplit_kernel).
// 128x128 tile, 256 threads = 4 waves in 2x2, each wave 2x2 of 32x32 tiles.
// mfma_f32_32x32x16_bf16: A-frag lane L: row=L&31, k=(L>>5)*8+j (b128 read);
// B-frag: col=L&31, same k; C/D: col=lane&31, row=(reg&3)+8*(reg>>2)+4*(L>>5).
// LDS [row][k] bf16, stride 40 shorts (80 B): 16B-aligned frags, uniform banks.
template<bool EPI>
__global__ __launch_bounds__(256) void gemm_mfma(
    const float* __restrict__ A, const u16* __restrict__ Bhi, const u16* __restrict__ Blo,
    float* __restrict__ C, int K, int M,
    const float* __restrict__ innorm, const float* __restrict__ bias){
  __shared__ u16 sAhi[128*40];
  __shared__ u16 sAlo[128*40];
  __shared__ u16 sBhi[128*40];
  __shared__ u16 sBlo[128*40];
  int tid = threadIdx.x;
  int row0 = blockIdx.x*128, col0 = blockIdx.y*128;
  int wv = tid >> 6, L = tid & 63;
  int wr = (wv >> 1)*64, wc = (wv & 1)*64;
  int srow = tid >> 1, skh = (tid & 1)*16;     // staging: row/col 0..127, k-half

  float16v acc[2][2];
  #pragma unroll
  for(int i = 0; i < 2; i++)
    #pragma unroll
    for(int j = 0; j < 2; j++)
      #pragma unroll
      for(int r = 0; r < 16; r++) acc[i][j][r] = 0.f;

  const float* Arow = A + (size_t)(row0 + srow)*K;
  bool av = (row0 + srow) < NN;
  bool bv = (col0 + srow) < M;
  const u16* bhsrc = Bhi + (size_t)(col0 + srow)*K;
  const u16* blsrc = Blo + (size_t)(col0 + srow)*K;
  const uint4 z4 = make_uint4(0,0,0,0);

  for(int k0 = 0; k0 < K; k0 += 32){
    // ---- global loads (before barrier, maximize overlap) ----
    float4 af0 = {0,0,0,0}, af1 = {0,0,0,0}, af2 = {0,0,0,0}, af3 = {0,0,0,0};
    if(av){
      af0 = *(const float4*)&Arow[k0 + skh];
      af1 = *(const float4*)&Arow[k0 + skh + 4];
      af2 = *(const float4*)&Arow[k0 + skh + 8];
      af3 = *(const float4*)&Arow[k0 + skh + 12];
    }
    uint4 bh0 = z4, bh1 = z4, bl0 = z4, bl1 = z4;
    if(bv){
      bh0 = *(const uint4*)&bhsrc[k0 + skh];
      bh1 = *(const uint4*)&bhsrc[k0 + skh + 8];
      bl0 = *(const uint4*)&blsrc[k0 + skh];
      bl1 = *(const uint4*)&blsrc[k0 + skh + 8];
    }
    // ---- split A to bf16 hi/lo, pack pairs ----
    unsigned h0,h1,h2,h3,h4,h5,h6,h7, l0,l1,l2,l3,l4,l5,l6,l7;
    split2(af0.x, af0.y, h0, l0); split2(af0.z, af0.w, h1, l1);
    split2(af1.x, af1.y, h2, l2); split2(af1.z, af1.w, h3, l3);
    split2(af2.x, af2.y, h4, l4); split2(af2.z, af2.w, h5, l5);
    split2(af3.x, af3.y, h6, l6); split2(af3.z, af3.w, h7, l7);
    __syncthreads();   // previous iteration's frag reads complete
    int sa = srow*40 + skh;
    *(uint4*)&sAhi[sa]     = make_uint4(h0,h1,h2,h3);
    *(uint4*)&sAhi[sa + 8] = make_uint4(h4,h5,h6,h7);
    *(uint4*)&sAlo[sa]     = make_uint4(l0,l1,l2,l3);
    *(uint4*)&sAlo[sa + 8] = make_uint4(l4,l5,l6,l7);
    *(uint4*)&sBhi[sa]     = bh0;
    *(uint4*)&sBhi[sa + 8] = bh1;
    *(uint4*)&sBlo[sa]     = bl0;
    *(uint4*)&sBlo[sa + 8] = bl1;
    __syncthreads();
    // ---- 2 MFMA k16-steps ----
    #pragma unroll
    for(int ks = 0; ks < 2; ks++){
      int ko = ks*16 + (L >> 5)*8;
      int ra0 = (wr + (L & 31))*40 + ko, ra1 = ra0 + 32*40;
      int rb0 = (wc + (L & 31))*40 + ko, rb1 = rb0 + 32*40;
      short8v ah0 = *(const short8v*)&sAhi[ra0];
      short8v ah1 = *(const short8v*)&sAhi[ra1];
      short8v al0 = *(const short8v*)&sAlo[ra0];
      short8v al1 = *(const short8v*)&sAlo[ra1];
      short8v bhf0 = *(const short8v*)&sBhi[rb0];
      short8v bhf1 = *(const short8v*)&sBhi[rb1];
      short8v blf0 = *(const short8v*)&sBlo[rb0];
      short8v blf1 = *(const short8v*)&sBlo[rb1];
      acc[0][0] = __builtin_amdgcn_mfma_f32_32x32x16_bf16(ah0, bhf0, acc[0][0], 0,0,0);
      acc[0][0] = __builtin_amdgcn_mfma_f32_32x32x16_bf16(al0, bhf0, acc[0][0], 0,0,0);
      acc[0][0] = __builtin_amdgcn_mfma_f32_32x32x16_bf16(ah0, blf0, acc[0][0], 0,0,0);
      acc[0][1] = __builtin_amdgcn_mfma_f32_32x32x16_bf16(ah0, bhf1, acc[0][1], 0,0,0);
      acc[0][1] = __builtin_amdgcn_mfma_f32_32x32x16_bf16(al0, bhf1, acc[0][1], 0,0,0);
      acc[0][1] = __builtin_amdgcn_mfma_f32_32x32x16_bf16(ah0, blf1, acc[0][1], 0,0,0);
      acc[1][0] = __builtin_amdgcn_mfma_f32_32x32x16_bf16(ah1, bhf0, acc[1][0], 0,0,0);
      acc[1][0] = __builtin_amdgcn_mfma_f32_32x32x16_bf16(al1, bhf0, acc[1][0], 0,0,0);
      acc[1][0] = __builtin_amdgcn_mfma_f32_32x32x16_bf16(ah1, blf0, acc[1][0], 0,0,0);
      acc[1][1] = __builtin_amdgcn_mfma_f32_32x32x16_bf16(ah1, bhf1, acc[1][1], 0,0,0);
      acc[1][1] = __builtin_amdgcn_mfma_f32_32x32x16_bf16(al1, bhf1, acc[1][1], 0,0,0);
      acc[1][1] = __builtin_amdgcn_mfma_f32_32x32x16_bf16(ah1, blf1, acc[1][1], 0,0,0);
    }
  }

  // ---- epilogue: C/D layout col=L&31, row=(reg&3)+8*(reg>>2)+4*(L>>5) ----
  int cB = L & 31, rq = 4*(L >> 5);
  #pragma unroll
  for(int tr = 0; tr < 2; tr++){
    #pragma unroll
    for(int tc = 0; tc < 2; tc++){
      int c = col0 + wc + tc*32 + cB;
      if(c >= M) continue;
      #pragma unroll
      for(int reg = 0; reg < 16; reg++){
        int r = row0 + wr + tr*32 + (reg & 3) + 8*(reg >> 2) + rq;
        if(r >= NN) continue;
        float v = acc[tr][tc][reg];
        if(EPI) v = fmaxf(v*innorm[r] + bias[c], 0.f);
        C[(size_t)r*M + c] = v;
      }
    }
  }
}

// ---------------- predictor (R4-exact, benched 255 us) -----------------------
#define ZS 68
__global__ __launch_bounds__(256) void predictor_kernel(
    const float* __restrict__ h3, const int* __restrict__ ps, const int* __restrict__ pd,
    const int* __restrict__ ns, const int* __restrict__ nd,
    const float* __restrict__ P1, const float* __restrict__ pb1,
    const float* __restrict__ P2, const float* __restrict__ pb2,
    const float* __restrict__ P3, const float* __restrict__ pb3,
    float* __restrict__ out){
  __shared__ float smem[13440];
  float* z   = smem;            // [160][ZS]
  float* p1p = smem + 160*ZS;   // [32][80]
  float* y1  = smem;            // [80][65]
  float* p2  = smem + 5200;     // [80][40]
  float* y2  = smem + 8400;     // [40][65]
  int tid = threadIdx.x;
  int pair0 = blockIdx.x*64;

  {
    int p = tid >> 2, sub = tid & 3;
    int q = pair0 + p;
    int a, b;
    if(q < NPAIR){ a = ps[q]; b = pd[q]; }
    else         { a = ns[q-NPAIR]; b = nd[q-NPAIR]; }
    const float4* ra = (const float4*)(h3 + (size_t)a*160);
    const float4* rb = (const float4*)(h3 + (size_t)b*160);
    #pragma unroll
    for(int it = 0; it < 10; it++){
      int g = sub + it*4;
      float4 va = ra[g], vb = rb[g];
      int k = g*4;
      z[(k+0)*ZS + p] = va.x*vb.x;
      z[(k+1)*ZS + p] = va.y*vb.y;
      z[(k+2)*ZS + p] = va.z*vb.z;
      z[(k+3)*ZS + p] = va.w*vb.w;
    }
  }

  int tr = tid >> 4, tc = tid & 15;
  float acc1[4][5];
  #pragma unroll
  for(int j = 0; j < 5; j++){
    float bv = pb1[tc + 16*j];
    #pragma unroll
    for(int i = 0; i < 4; i++) acc1[i][j] = bv;
  }
  for(int k0 = 0; k0 < 160; k0 += 32){
    __syncthreads();
    const float4* gp = (const float4*)(P1 + k0*80);
    for(int i = tid; i < 640; i += 256) ((float4*)p1p)[i] = gp[i];
    __syncthreads();
    #pragma unroll 8
    for(int kk = 0; kk < 32; kk++){
      float4 av = *(const float4*)&z[(k0+kk)*ZS + tr*4];
      float a0 = av.x, a1 = av.y, a2 = av.z, a3 = av.w;
      float b[5];
      #pragma unroll
      for(int j = 0; j < 5; j++) b[j] = p1p[kk*80 + tc + 16*j];
      #pragma unroll
      for(int j = 0; j < 5; j++){
        acc1[0][j] += a0*b[j];
        acc1[1][j] += a1*b[j];
        acc1[2][j] += a2*b[j];
        acc1[3][j] += a3*b[j];
      }
    }
  }
  __syncthreads();

  #pragma unroll
  for(int i = 0; i < 4; i++)
    #pragma unroll
    for(int j = 0; j < 5; j++)
      y1[(tc + 16*j)*65 + tr*4 + i] = leaky(acc1[i][j]);
  for(int i = tid; i < 800; i += 256) ((float4*)p2)[i] = ((const float4*)P2)[i];
  __syncthreads();

  int tr2 = tid >> 3, tc2 = tid & 7;
  float acc2[2][5];
  #pragma unroll
  for(int j = 0; j < 5; j++){
    float bv = pb2[tc2 + 8*j];
    acc2[0][j] = bv; acc2[1][j] = bv;
  }
  #pragma unroll 4
  for(int k = 0; k < 80; k++){
    float a0 = y1[k*65 + tr2*2], a1 = y1[k*65 + tr2*2 + 1];
    #pragma unroll
    for(int j = 0; j < 5; j++){
      float bv = p2[k*40 + tc2 + 8*j];
      acc2[0][j] += a0*bv;
      acc2[1][j] += a1*bv;
    }
  }
  #pragma unroll
  for(int i = 0; i < 2; i++)
    #pragma unroll
    for(int j = 0; j < 5; j++)
      y2[(tc2 + 8*j)*65 + tr2*2 + i] = leaky(acc2[i][j]);
  __syncthreads();

  if(tid < 64){
    float s = pb3[0];
    #pragma unroll 8
    for(int k = 0; k < 40; k++) s += y2[k*65 + tid]*P3[k];
    out[pair0 + tid] = s;
  }
}

// ---------------- launch ----------------

extern "C" void kernel_launch(void* const* d_in, const int* in_sizes, int n_in,
                              void* d_out, int out_size, void* d_ws, size_t ws_size,
                              hipStream_t stream) {
  const float* x  = (const float*)d_in[0];
  const float* w  = (const float*)d_in[1];
  const int* src  = (const int*)d_in[2];
  const int* dst  = (const int*)d_in[3];
  const int* ps   = (const int*)d_in[4];
  const int* pd   = (const int*)d_in[5];
  const int* ns   = (const int*)d_in[6];
  const int* nd   = (const int*)d_in[7];
  const float* W1 = (const float*)d_in[8];  const float* b1  = (const float*)d_in[9];
  const float* W2 = (const float*)d_in[10]; const float* b2  = (const float*)d_in[11];
  const float* W3 = (const float*)d_in[12]; const float* b3  = (const float*)d_in[13];
  const float* P1 = (const float*)d_in[14]; const float* pb1 = (const float*)d_in[15];
  const float* P2 = (const float*)d_in[16]; const float* pb2 = (const float*)d_in[17];
  const float* P3 = (const float*)d_in[18]; const float* pb3 = (const float*)d_in[19];
  float* out = (float*)d_out;

  char* p = (char*)d_ws;
  auto alloc = [&](size_t bytes)->char*{
    char* r = p; p += (bytes + 255) & ~(size_t)255; return r;
  };
  int*   cnt_out = (int*)  alloc(NN*4);          // these three must stay contiguous
  int*   cnt_in  = (int*)  alloc(NN*4);          // (zeroed with one memset)
  int*   fill    = (int*)  alloc(NN*4);
  int*   row_off = (int*)  alloc((NN+1)*4);
  float* out_nrm = (float*)alloc(NN*4);
  float* in_nrm  = (float*)alloc(NN*4);
  int*   es      = (int*)  alloc((size_t)EE*4);
  float* ew      = (float*)alloc((size_t)EE*4);
  u16*   w1h     = (u16*)  alloc(256*512*2);
  u16*   w1l     = (u16*)  alloc(256*512*2);
  u16*   w2h     = (u16*)  alloc(512*256*2);
  u16*   w2l     = (u16*)  alloc(512*256*2);
  u16*   w3h     = (u16*)  alloc(256*160*2);
  u16*   w3l     = (u16*)  alloc(256*160*2);
  float* bufA    = (float*)alloc((size_t)NN*512*4);  // h1 (N x 512)
  float* bufB    = (float*)alloc((size_t)NN*256*4);  // proj2 / proj3
  float* bufC    = (float*)alloc((size_t)NN*256*4);  // agg1 / h2

  size_t cntPad = (NN*4 + 255) & ~(size_t)255;
  hipMemsetAsync(cnt_out, 0, 3*cntPad, stream);

  degree_kernel<<<(EE+255)/256, 256, 0, stream>>>(src, dst, cnt_out, cnt_in);
  norm_kernel<<<(NN+255)/256, 256, 0, stream>>>(cnt_out, cnt_in, out_nrm, in_nrm);
  scan_kernel<<<1, 512, 0, stream>>>(cnt_in, row_off);
  bucket_kernel<<<(EE+255)/256, 256, 0, stream>>>(src, dst, w, out_nrm, row_off, fill, es, ew);
  wsplit_kernel<<<512, 256, 0, stream>>>(W1, 256, 512, w1h, w1l);
  wsplit_kernel<<<512, 256, 0, stream>>>(W2, 512, 256, w2h, w2l);
  wsplit_kernel<<<160, 256, 0, stream>>>(W3, 256, 160, w3h, w3l);

  int aggGrid = (NN + 3)/4;

  // layer 1: agg(x, ew2) @ W1, epilogue relu(*in_norm + b1)
  agg_kernel<256,0><<<aggGrid, 256, 0, stream>>>(x, es, ew, row_off, nullptr, nullptr, bufC);
  gemm_mfma<true><<<dim3(391,4), 256, 0, stream>>>(bufC, w1h, w1l, bufA, 256, 512, in_nrm, b1);

  // layer 2: agg(h1 @ W2, ew2), fused epilogue relu(*in_norm + b2)
  gemm_mfma<false><<<dim3(391,2), 256, 0, stream>>>(bufA, w2h, w2l, bufB, 512, 256, nullptr, nullptr);
  agg_kernel<256,1><<<aggGrid, 256, 0, stream>>>(bufB, es, ew, row_off, in_nrm, b2, bufC);

  // layer 3: agg(h2 @ W3, ew2), fused epilogue *in_norm + b3 -> d_out h region
  gemm_mfma<false><<<dim3(391,2), 256, 0, stream>>>(bufC, w3h, w3l, bufB, 256, 160, nullptr, nullptr);
  agg_kernel<160,2><<<aggGrid, 256, 0, stream>>>(bufB, es, ew, row_off, in_nrm, b3, out + 2*NPAIR);

  // predictor on pos+neg pairs
  predictor_kernel<<<(2*NPAIR)/64, 256, 0, stream>>>(out + 2*NPAIR, ps, pd, ns, nd,
                                                     P1, pb1, P2, pb2, P3, pb3, out);
}

// Round 10
// 944.341 us; speedup vs baseline: 3.2898x; 1.1034x over previous
//
#include <hip/hip_runtime.h>
#include <math.h>

#define NN 50000
#define EE 800000
#define NPAIR 200000

typedef unsigned short u16;
typedef short short8v __attribute__((ext_vector_type(8)));
typedef float float16v __attribute__((ext_vector_type(16)));

__device__ __forceinline__ float leaky(float x){ return x >= 0.f ? x : 0.2f*x; }

// bf16 round-to-nearest-even helpers for the hi/lo split
__device__ __forceinline__ u16 bfhi(float x){
  union{float f; unsigned u;} v; v.f = x;
  unsigned r = (v.u + 0x7FFFu + ((v.u >> 16) & 1u)) >> 16;
  return (u16)r;
}
__device__ __forceinline__ float bf2f(u16 h){
  union{unsigned u; float f;} v; v.u = ((unsigned)h) << 16; return v.f;
}
__device__ __forceinline__ void split2(float x, float y, unsigned &hp, unsigned &lp){
  u16 hx = bfhi(x), hy = bfhi(y);
  u16 lx = bfhi(x - bf2f(hx)), ly = bfhi(y - bf2f(hy));
  hp = (unsigned)hx | ((unsigned)hy << 16);
  lp = (unsigned)lx | ((unsigned)ly << 16);
}
#define MFMA_BF16 __builtin_amdgcn_mfma_f32_32x32x16_bf16

// ---------------- degree / norms / CSR build ----------------

__global__ void degree_kernel(const int* __restrict__ src, const int* __restrict__ dst,
                              int* cnt_out, int* cnt_in){
  int i = blockIdx.x*blockDim.x + threadIdx.x;
  if(i < EE){
    atomicAdd(&cnt_out[src[i]], 1);
    atomicAdd(&cnt_in[dst[i]], 1);
  }
}

__global__ void norm_kernel(const int* __restrict__ cnt_out, const int* __restrict__ cnt_in,
                            float* __restrict__ out_norm, float* __restrict__ in_norm){
  int i = blockIdx.x*blockDim.x + threadIdx.x;
  if(i < NN){
    int o = cnt_out[i]; if(o < 1) o = 1;
    int d = cnt_in[i];  if(d < 1) d = 1;
    out_norm[i] = 1.f/sqrtf((float)o);
    in_norm[i]  = 1.f/sqrtf((float)d);
  }
}

// single-block exclusive scan of cnt_in[NN] -> row_off[NN+1]
__global__ void scan_kernel(const int* __restrict__ cnt, int* __restrict__ row_off){
  const int T = 512;
  __shared__ int sums[T];
  int t = threadIdx.x;
  int chunk = (NN + T - 1)/T;
  int base = t*chunk;
  int hi = base + chunk; if(hi > NN) hi = NN;
  int s = 0;
  for(int i = base; i < hi; i++) s += cnt[i];
  sums[t] = s;
  __syncthreads();
  for(int off = 1; off < T; off <<= 1){
    int add = (t >= off) ? sums[t-off] : 0;
    __syncthreads();
    sums[t] += add;
    __syncthreads();
  }
  int run = sums[t] - s;
  for(int i = base; i < hi; i++){ row_off[i] = run; run += cnt[i]; }
  if(t == T-1) row_off[NN] = EE;
}

// ew2 = w * out_norm[src]: out_norm commutes with @W, folded into edge weight.
__global__ void bucket_kernel(const int* __restrict__ src, const int* __restrict__ dst,
                              const float* __restrict__ w, const float* __restrict__ out_norm,
                              const int* __restrict__ row_off,
                              int* fill, int* __restrict__ es, float* __restrict__ ew){
  int i = blockIdx.x*blockDim.x + threadIdx.x;
  if(i < EE){
    int d = dst[i];
    int s = src[i];
    int p = row_off[d] + atomicAdd(&fill[d], 1);
    es[p] = s;
    ew[p] = w[i] * out_norm[s];
  }
}

// W (K x M fp32, row-major) -> Wt_hi / Wt_lo (M x K bf16), transposed.
__global__ void wsplit_kernel(const float* __restrict__ W, int K, int M,
                              u16* __restrict__ Whi, u16* __restrict__ Wlo){
  int i = blockIdx.x*256 + threadIdx.x;     // i = m*K + k
  if(i < K*M){
    int m = i / K, k = i - m*K;
    float a = W[(size_t)k*M + m];
    u16 h = bfhi(a);
    Whi[i] = h;
    Wlo[i] = bfhi(a - bf2f(h));
  }
}

// P1 (160x80) -> P1t hi/lo [96 cols][160 k] (cols 80..95 zero);
// P2 (80x40)  -> P2t hi/lo [64 cols][80 k]  (cols 40..63 zero).
__global__ void psplit_kernel(const float* __restrict__ P1, const float* __restrict__ P2,
                              u16* __restrict__ P1th, u16* __restrict__ P1tl,
                              u16* __restrict__ P2th, u16* __restrict__ P2tl){
  int i = blockIdx.x*256 + threadIdx.x;
  if(i < 96*160){
    int c = i/160, k = i - c*160;
    float v = (c < 80) ? P1[k*80 + c] : 0.f;
    u16 h = bfhi(v);
    P1th[i] = h; P1tl[i] = bfhi(v - bf2f(h));
  }
  if(i < 64*80){
    int c = i/80, k = i - c*80;
    float v = (c < 40) ? P2[k*40 + c] : 0.f;
    u16 h = bfhi(v);
    P2th[i] = h; P2tl[i] = bfhi(v - bf2f(h));
  }
}

// ---------------- aggregation v3: one WAVE per node (R8, proven) -------------
template<int F, int MODE>
__global__ __launch_bounds__(256) void agg_kernel(
    const float* __restrict__ feat, const int* __restrict__ es,
    const float* __restrict__ ew, const int* __restrict__ row_off,
    const float* __restrict__ innorm, const float* __restrict__ bias,
    float* __restrict__ out){
  constexpr int F4 = F/4;
  int wid = threadIdx.x >> 6, lane = threadIdx.x & 63;
  int v = blockIdx.x*4 + wid;
  if(v >= NN || lane >= F4) return;
  int s = row_off[v], e = row_off[v+1];
  const float4* f4 = (const float4*)feat;
  float4 a0 = {0,0,0,0}, a1 = {0,0,0,0}, a2 = {0,0,0,0}, a3 = {0,0,0,0};
  int j = s;
  for(; j + 3 < e; j += 4){
    int   i0 = es[j],   i1 = es[j+1], i2 = es[j+2], i3 = es[j+3];
    float w0 = ew[j],   w1 = ew[j+1], w2 = ew[j+2], w3 = ew[j+3];
    float4 r0 = f4[(size_t)i0*F4 + lane];
    float4 r1 = f4[(size_t)i1*F4 + lane];
    float4 r2 = f4[(size_t)i2*F4 + lane];
    float4 r3 = f4[(size_t)i3*F4 + lane];
    a0.x += r0.x*w0; a0.y += r0.y*w0; a0.z += r0.z*w0; a0.w += r0.w*w0;
    a1.x += r1.x*w1; a1.y += r1.y*w1; a1.z += r1.z*w1; a1.w += r1.w*w1;
    a2.x += r2.x*w2; a2.y += r2.y*w2; a2.z += r2.z*w2; a2.w += r2.w*w2;
    a3.x += r3.x*w3; a3.y += r3.y*w3; a3.z += r3.z*w3; a3.w += r3.w*w3;
  }
  for(; j < e; j++){
    int idx = es[j]; float wt = ew[j];
    float4 r = f4[(size_t)idx*F4 + lane];
    a0.x += r.x*wt; a0.y += r.y*wt; a0.z += r.z*wt; a0.w += r.w*wt;
  }
  float4 r;
  r.x = (a0.x+a1.x)+(a2.x+a3.x);
  r.y = (a0.y+a1.y)+(a2.y+a3.y);
  r.z = (a0.z+a1.z)+(a2.z+a3.z);
  r.w = (a0.w+a1.w)+(a2.w+a3.w);
  if(MODE >= 1){
    float inm = innorm[v];
    float4 bb = *(const float4*)&bias[lane*4];
    r.x = r.x*inm + bb.x; r.y = r.y*inm + bb.y;
    r.z = r.z*inm + bb.z; r.w = r.w*inm + bb.w;
    if(MODE == 1){
      r.x = fmaxf(r.x, 0.f); r.y = fmaxf(r.y, 0.f);
      r.z = fmaxf(r.z, 0.f); r.w = fmaxf(r.w, 0.f);
    }
  }
  ((float4*)(out + (size_t)v*F))[lane] = r;
}

// ---------------- GEMM via MFMA bf16x2-split (R9, proven) --------------------
template<bool EPI>
__global__ __launch_bounds__(256) void gemm_mfma(
    const float* __restrict__ A, const u16* __restrict__ Bhi, const u16* __restrict__ Blo,
    float* __restrict__ C, int K, int M,
    const float* __restrict__ innorm, const float* __restrict__ bias){
  __shared__ u16 sAhi[128*40];
  __shared__ u16 sAlo[128*40];
  __shared__ u16 sBhi[128*40];
  __shared__ u16 sBlo[128*40];
  int tid = threadIdx.x;
  int row0 = blockIdx.x*128, col0 = blockIdx.y*128;
  int wv = tid >> 6, L = tid & 63;
  int wr = (wv >> 1)*64, wc = (wv & 1)*64;
  int srow = tid >> 1, skh = (tid & 1)*16;

  float16v acc[2][2];
  #pragma unroll
  for(int i = 0; i < 2; i++)
    #pragma unroll
    for(int j = 0; j < 2; j++)
      #pragma unroll
      for(int r = 0; r < 16; r++) acc[i][j][r] = 0.f;

  const float* Arow = A + (size_t)(row0 + srow)*K;
  bool av = (row0 + srow) < NN;
  bool bv = (col0 + srow) < M;
  const u16* bhsrc = Bhi + (size_t)(col0 + srow)*K;
  const u16* blsrc = Blo + (size_t)(col0 + srow)*K;
  const uint4 z4 = make_uint4(0,0,0,0);

  for(int k0 = 0; k0 < K; k0 += 32){
    float4 af0 = {0,0,0,0}, af1 = {0,0,0,0}, af2 = {0,0,0,0}, af3 = {0,0,0,0};
    if(av){
      af0 = *(const float4*)&Arow[k0 + skh];
      af1 = *(const float4*)&Arow[k0 + skh + 4];
      af2 = *(const float4*)&Arow[k0 + skh + 8];
      af3 = *(const float4*)&Arow[k0 + skh + 12];
    }
    uint4 bh0 = z4, bh1 = z4, bl0 = z4, bl1 = z4;
    if(bv){
      bh0 = *(const uint4*)&bhsrc[k0 + skh];
      bh1 = *(const uint4*)&bhsrc[k0 + skh + 8];
      bl0 = *(const uint4*)&blsrc[k0 + skh];
      bl1 = *(const uint4*)&blsrc[k0 + skh + 8];
    }
    unsigned h0,h1,h2,h3,h4,h5,h6,h7, l0,l1,l2,l3,l4,l5,l6,l7;
    split2(af0.x, af0.y, h0, l0); split2(af0.z, af0.w, h1, l1);
    split2(af1.x, af1.y, h2, l2); split2(af1.z, af1.w, h3, l3);
    split2(af2.x, af2.y, h4, l4); split2(af2.z, af2.w, h5, l5);
    split2(af3.x, af3.y, h6, l6); split2(af3.z, af3.w, h7, l7);
    __syncthreads();
    int sa = srow*40 + skh;
    *(uint4*)&sAhi[sa]     = make_uint4(h0,h1,h2,h3);
    *(uint4*)&sAhi[sa + 8] = make_uint4(h4,h5,h6,h7);
    *(uint4*)&sAlo[sa]     = make_uint4(l0,l1,l2,l3);
    *(uint4*)&sAlo[sa + 8] = make_uint4(l4,l5,l6,l7);
    *(uint4*)&sBhi[sa]     = bh0;
    *(uint4*)&sBhi[sa + 8] = bh1;
    *(uint4*)&sBlo[sa]     = bl0;
    *(uint4*)&sBlo[sa + 8] = bl1;
    __syncthreads();
    #pragma unroll
    for(int ks = 0; ks < 2; ks++){
      int ko = ks*16 + (L >> 5)*8;
      int ra0 = (wr + (L & 31))*40 + ko, ra1 = ra0 + 32*40;
      int rb0 = (wc + (L & 31))*40 + ko, rb1 = rb0 + 32*40;
      short8v ah0 = *(const short8v*)&sAhi[ra0];
      short8v ah1 = *(const short8v*)&sAhi[ra1];
      short8v al0 = *(const short8v*)&sAlo[ra0];
      short8v al1 = *(const short8v*)&sAlo[ra1];
      short8v bhf0 = *(const short8v*)&sBhi[rb0];
      short8v bhf1 = *(const short8v*)&sBhi[rb1];
      short8v blf0 = *(const short8v*)&sBlo[rb0];
      short8v blf1 = *(const short8v*)&sBlo[rb1];
      acc[0][0] = MFMA_BF16(ah0, bhf0, acc[0][0], 0,0,0);
      acc[0][0] = MFMA_BF16(al0, bhf0, acc[0][0], 0,0,0);
      acc[0][0] = MFMA_BF16(ah0, blf0, acc[0][0], 0,0,0);
      acc[0][1] = MFMA_BF16(ah0, bhf1, acc[0][1], 0,0,0);
      acc[0][1] = MFMA_BF16(al0, bhf1, acc[0][1], 0,0,0);
      acc[0][1] = MFMA_BF16(ah0, blf1, acc[0][1], 0,0,0);
      acc[1][0] = MFMA_BF16(ah1, bhf0, acc[1][0], 0,0,0);
      acc[1][0] = MFMA_BF16(al1, bhf0, acc[1][0], 0,0,0);
      acc[1][0] = MFMA_BF16(ah1, blf0, acc[1][0], 0,0,0);
      acc[1][1] = MFMA_BF16(ah1, bhf1, acc[1][1], 0,0,0);
      acc[1][1] = MFMA_BF16(al1, bhf1, acc[1][1], 0,0,0);
      acc[1][1] = MFMA_BF16(ah1, blf1, acc[1][1], 0,0,0);
    }
  }

  int cB = L & 31, rq = 4*(L >> 5);
  #pragma unroll
  for(int tr = 0; tr < 2; tr++){
    #pragma unroll
    for(int tc = 0; tc < 2; tc++){
      int c = col0 + wc + tc*32 + cB;
      if(c >= M) continue;
      #pragma unroll
      for(int reg = 0; reg < 16; reg++){
        int r = row0 + wr + tr*32 + (reg & 3) + 8*(reg >> 2) + rq;
        if(r >= NN) continue;
        float v = acc[tr][tc][reg];
        if(EPI) v = fmaxf(v*innorm[r] + bias[c], 0.f);
        C[(size_t)r*M + c] = v;
      }
    }
  }
}

// ---------------- predictor v6: MFMA bf16x2-split, 64 pairs/block ------------
// z gathered ONCE (R4 lesson), split to bf16 hi/lo [pair][k] (stride 168
// shorts = 336 B == 16 mod 64 -> conflict-free b128 frags). Stage 1: 6 tile
// jobs (2 pair-tiles x 3 col-tiles, cols 80..95 zero-padded), P1 in 16-k LDS
// panels behind barriers (R4's proven pattern). y1: +pb1, leaky in fp32, then
// re-split. Stage 2: 4 jobs (1/wave). Stage 3: P3 scale + shfl_xor butterfly.
// LDS 52224 B -> 3 blocks/CU (occupancy lesson from R6).
#define ZSTR 168
#define P1STR 24
#define Y1STR 88
__global__ __launch_bounds__(256) void predictor_mfma(
    const float* __restrict__ h3,
    const int* __restrict__ ps, const int* __restrict__ pd,
    const int* __restrict__ ns, const int* __restrict__ nd,
    const u16* __restrict__ P1th, const u16* __restrict__ P1tl,
    const float* __restrict__ pb1,
    const u16* __restrict__ P2th, const u16* __restrict__ P2tl,
    const float* __restrict__ pb2,
    const float* __restrict__ P3, const float* __restrict__ pb3,
    float* __restrict__ out){
  __shared__ u16 smem[26112];          // 52224 B
  u16* zh  = smem;                     // [64][168]
  u16* zl  = smem + 64*ZSTR;
  u16* p1h = smem + 2*64*ZSTR;         // [96][24] panel
  u16* p1l = p1h + 96*P1STR;
  u16* y1h = smem;                     // phase B: [64][88]
  u16* y1l = smem + 64*Y1STR;
  u16* p2h = smem + 2*64*Y1STR;        // [64][88]
  u16* p2l = smem + 3*64*Y1STR;
  float* part = (float*)(smem + 4*64*Y1STR);   // [2][64] floats

  int tid = threadIdx.x;
  int pair0 = blockIdx.x*64;           // grid = 400000/64 = 6250 exactly
  int w = tid >> 6, L = tid & 63;
  int lrow = L & 31, lk = (L >> 5)*8;

  // ---- gather z, split to bf16 hi/lo [pair][k] ----
  {
    int p = tid >> 2, sub = tid & 3;
    int q = pair0 + p;
    int a, b;
    if(q < NPAIR){ a = ps[q]; b = pd[q]; }
    else         { a = ns[q-NPAIR]; b = nd[q-NPAIR]; }
    const float4* ra = (const float4*)(h3 + (size_t)a*160);
    const float4* rb = (const float4*)(h3 + (size_t)b*160);
    #pragma unroll
    for(int it = 0; it < 10; it++){
      int g = sub + it*4;
      float4 va = ra[g], vb = rb[g];
      unsigned hp0, lp0, hp1, lp1;
      split2(va.x*vb.x, va.y*vb.y, hp0, lp0);
      split2(va.z*vb.z, va.w*vb.w, hp1, lp1);
      *(uint2*)&zh[p*ZSTR + 4*g] = make_uint2(hp0, hp1);
      *(uint2*)&zl[p*ZSTR + 4*g] = make_uint2(lp0, lp1);
    }
  }

  // ---- stage 1: jobs (pt,ct) = j/3, j%3; wave w -> j1=w, j2=w+4 (w<2) ----
  float16v acc1a, acc1b;
  #pragma unroll
  for(int r = 0; r < 16; r++){ acc1a[r] = 0.f; acc1b[r] = 0.f; }
  int j1 = w, j2 = (w < 2) ? (w + 4) : -1;
  int pt1 = j1/3, ct1 = j1 - pt1*3;
  int pt2 = (j2 >= 0) ? j2/3 : 0;
  int ct2j = (j2 >= 0) ? (j2 - pt2*3) : 0;

  for(int k0 = 0; k0 < 160; k0 += 16){
    __syncthreads();                   // z visible (iter 0) / prev panel reads done
    if(tid < 192){
      int c = tid >> 1, half = tid & 1;
      uint4 vh = *(const uint4*)&P1th[c*160 + k0 + half*8];
      uint4 vl = *(const uint4*)&P1tl[c*160 + k0 + half*8];
      *(uint4*)&p1h[c*P1STR + half*8] = vh;
      *(uint4*)&p1l[c*P1STR + half*8] = vl;
    }
    __syncthreads();
    {
      short8v ah = *(const short8v*)&zh[(pt1*32 + lrow)*ZSTR + k0 + lk];
      short8v al = *(const short8v*)&zl[(pt1*32 + lrow)*ZSTR + k0 + lk];
      short8v bh = *(const short8v*)&p1h[(ct1*32 + lrow)*P1STR + lk];
      short8v bl = *(const short8v*)&p1l[(ct1*32 + lrow)*P1STR + lk];
      acc1a = MFMA_BF16(ah, bh, acc1a, 0,0,0);
      acc1a = MFMA_BF16(al, bh, acc1a, 0,0,0);
      acc1a = MFMA_BF16(ah, bl, acc1a, 0,0,0);
    }
    if(j2 >= 0){
      short8v ah = *(const short8v*)&zh[(pt2*32 + lrow)*ZSTR + k0 + lk];
      short8v al = *(const short8v*)&zl[(pt2*32 + lrow)*ZSTR + k0 + lk];
      short8v bh = *(const short8v*)&p1h[(ct2j*32 + lrow)*P1STR + lk];
      short8v bl = *(const short8v*)&p1l[(ct2j*32 + lrow)*P1STR + lk];
      acc1b = MFMA_BF16(ah, bh, acc1b, 0,0,0);
      acc1b = MFMA_BF16(al, bh, acc1b, 0,0,0);
      acc1b = MFMA_BF16(ah, bl, acc1b, 0,0,0);
    }
  }
  __syncthreads();                     // all z/panel reads done; region reused

  // ---- y1 epilogue (fp32 +pb1, leaky) -> bf16 hi/lo [pair][k=col]; stage P2 --
  {
    int c = ct1*32 + lrow;
    if(c < 80){
      float pb = pb1[c];
      #pragma unroll
      for(int r = 0; r < 16; r++){
        int p = pt1*32 + (r & 3) + 8*(r >> 2) + 4*(L >> 5);
        float v = leaky(acc1a[r] + pb);
        u16 h = bfhi(v);
        y1h[p*Y1STR + c] = h;
        y1l[p*Y1STR + c] = bfhi(v - bf2f(h));
      }
    }
  }
  if(j2 >= 0){
    int c = ct2j*32 + lrow;
    if(c < 80){
      float pb = pb1[c];
      #pragma unroll
      for(int r = 0; r < 16; r++){
        int p = pt2*32 + (r & 3) + 8*(r >> 2) + 4*(L >> 5);
        float v = leaky(acc1b[r] + pb);
        u16 h = bfhi(v);
        y1h[p*Y1STR + c] = h;
        y1l[p*Y1STR + c] = bfhi(v - bf2f(h));
      }
    }
  }
  for(int i = tid; i < 640; i += 256){
    int c = i/10, jj = i - c*10;
    *(uint4*)&p2h[c*Y1STR + jj*8] = *(const uint4*)&P2th[c*80 + jj*8];
    *(uint4*)&p2l[c*Y1STR + jj*8] = *(const uint4*)&P2tl[c*80 + jj*8];
  }
  __syncthreads();

  // ---- stage 2: wave w -> (pt = w&1, c2t = w>>1), K=80 ----
  float16v acc2;
  #pragma unroll
  for(int r = 0; r < 16; r++) acc2[r] = 0.f;
  int pt = w & 1, c2t = w >> 1;
  for(int k0 = 0; k0 < 80; k0 += 16){
    short8v ah = *(const short8v*)&y1h[(pt*32 + lrow)*Y1STR + k0 + lk];
    short8v al = *(const short8v*)&y1l[(pt*32 + lrow)*Y1STR + k0 + lk];
    short8v bh = *(const short8v*)&p2h[(c2t*32 + lrow)*Y1STR + k0 + lk];
    short8v bl = *(const short8v*)&p2l[(c2t*32 + lrow)*Y1STR + k0 + lk];
    acc2 = MFMA_BF16(ah, bh, acc2, 0,0,0);
    acc2 = MFMA_BF16(al, bh, acc2, 0,0,0);
    acc2 = MFMA_BF16(ah, bl, acc2, 0,0,0);
  }

  // ---- stage 3: leaky(+pb2) * P3[c], butterfly-reduce over 32-lane half ----
  int c2 = c2t*32 + lrow;
  float pb2c = (c2 < 40) ? pb2[c2] : 0.f;
  float p3c  = (c2 < 40) ? P3[c2]  : 0.f;
  float vals[16];
  #pragma unroll
  for(int r = 0; r < 16; r++){
    float v = leaky(acc2[r] + pb2c) * p3c;
    #pragma unroll
    for(int m = 1; m < 32; m <<= 1) v += __shfl_xor(v, m);
    vals[r] = v;
  }
  if(lrow == 0){
    #pragma unroll
    for(int r = 0; r < 16; r++){
      int p = pt*32 + (r & 3) + 8*(r >> 2) + 4*(L >> 5);
      part[c2t*64 + p] = vals[r];
    }
  }
  __syncthreads();
  if(tid < 64) out[pair0 + tid] = (part[tid] + part[64 + tid]) + pb3[0];
}

// ---------------- launch ----------------

extern "C" void kernel_launch(void* const* d_in, const int* in_sizes, int n_in,
                              void* d_out, int out_size, void* d_ws, size_t ws_size,
                              hipStream_t stream) {
  const float* x  = (const float*)d_in[0];
  const float* w  = (const float*)d_in[1];
  const int* src  = (const int*)d_in[2];
  const int* dst  = (const int*)d_in[3];
  const int* ps   = (const int*)d_in[4];
  const int* pd   = (const int*)d_in[5];
  const int* ns   = (const int*)d_in[6];
  const int* nd   = (const int*)d_in[7];
  const float* W1 = (const float*)d_in[8];  const float* b1  = (const float*)d_in[9];
  const float* W2 = (const float*)d_in[10]; const float* b2  = (const float*)d_in[11];
  const float* W3 = (const float*)d_in[12]; const float* b3  = (const float*)d_in[13];
  const float* P1 = (const float*)d_in[14]; const float* pb1 = (const float*)d_in[15];
  const float* P2 = (const float*)d_in[16]; const float* pb2 = (const float*)d_in[17];
  const float* P3 = (const float*)d_in[18]; const float* pb3 = (const float*)d_in[19];
  float* out = (float*)d_out;

  char* p = (char*)d_ws;
  auto alloc = [&](size_t bytes)->char*{
    char* r = p; p += (bytes + 255) & ~(size_t)255; return r;
  };
  int*   cnt_out = (int*)  alloc(NN*4);          // these three must stay contiguous
  int*   cnt_in  = (int*)  alloc(NN*4);          // (zeroed with one memset)
  int*   fill    = (int*)  alloc(NN*4);
  int*   row_off = (int*)  alloc((NN+1)*4);
  float* out_nrm = (float*)alloc(NN*4);
  float* in_nrm  = (float*)alloc(NN*4);
  int*   es      = (int*)  alloc((size_t)EE*4);
  float* ew      = (float*)alloc((size_t)EE*4);
  u16*   w1h     = (u16*)  alloc(256*512*2);
  u16*   w1l     = (u16*)  alloc(256*512*2);
  u16*   w2h     = (u16*)  alloc(512*256*2);
  u16*   w2l     = (u16*)  alloc(512*256*2);
  u16*   w3h     = (u16*)  alloc(256*160*2);
  u16*   w3l     = (u16*)  alloc(256*160*2);
  u16*   p1th    = (u16*)  alloc(96*160*2);
  u16*   p1tl    = (u16*)  alloc(96*160*2);
  u16*   p2th    = (u16*)  alloc(64*80*2);
  u16*   p2tl    = (u16*)  alloc(64*80*2);
  float* bufA    = (float*)alloc((size_t)NN*512*4);  // h1 (N x 512)
  float* bufB    = (float*)alloc((size_t)NN*256*4);  // proj2 / proj3
  float* bufC    = (float*)alloc((size_t)NN*256*4);  // agg1 / h2

  size_t cntPad = (NN*4 + 255) & ~(size_t)255;
  hipMemsetAsync(cnt_out, 0, 3*cntPad, stream);

  degree_kernel<<<(EE+255)/256, 256, 0, stream>>>(src, dst, cnt_out, cnt_in);
  norm_kernel<<<(NN+255)/256, 256, 0, stream>>>(cnt_out, cnt_in, out_nrm, in_nrm);
  scan_kernel<<<1, 512, 0, stream>>>(cnt_in, row_off);
  bucket_kernel<<<(EE+255)/256, 256, 0, stream>>>(src, dst, w, out_nrm, row_off, fill, es, ew);
  wsplit_kernel<<<512, 256, 0, stream>>>(W1, 256, 512, w1h, w1l);
  wsplit_kernel<<<512, 256, 0, stream>>>(W2, 512, 256, w2h, w2l);
  wsplit_kernel<<<160, 256, 0, stream>>>(W3, 256, 160, w3h, w3l);
  psplit_kernel<<<60, 256, 0, stream>>>(P1, P2, p1th, p1tl, p2th, p2tl);

  int aggGrid = (NN + 3)/4;

  // layer 1: agg(x, ew2) @ W1, epilogue relu(*in_norm + b1)
  agg_kernel<256,0><<<aggGrid, 256, 0, stream>>>(x, es, ew, row_off, nullptr, nullptr, bufC);
  gemm_mfma<true><<<dim3(391,4), 256, 0, stream>>>(bufC, w1h, w1l, bufA, 256, 512, in_nrm, b1);

  // layer 2: agg(h1 @ W2, ew2), fused epilogue relu(*in_norm + b2)
  gemm_mfma<false><<<dim3(391,2), 256, 0, stream>>>(bufA, w2h, w2l, bufB, 512, 256, nullptr, nullptr);
  agg_kernel<256,1><<<aggGrid, 256, 0, stream>>>(bufB, es, ew, row_off, in_nrm, b2, bufC);

  // layer 3: agg(h2 @ W3, ew2), fused epilogue *in_norm + b3 -> d_out h region
  gemm_mfma<false><<<dim3(391,2), 256, 0, stream>>>(bufC, w3h, w3l, bufB, 256, 160, nullptr, nullptr);
  agg_kernel<160,2><<<aggGrid, 256, 0, stream>>>(bufB, es, ew, row_off, in_nrm, b3, out + 2*NPAIR);

  // predictor on pos+neg pairs (MFMA)
  predictor_mfma<<<(2*NPAIR)/64, 256, 0, stream>>>(out + 2*NPAIR, ps, pd, ns, nd,
                                                   p1th, p1tl, pb1, p2th, p2tl, pb2,
                                                   P3, pb3, out);
}